// Round 7
// baseline (507.292 us; speedup 1.0000x reference)
//
#include <hip/hip_runtime.h>
#include <hip/hip_fp16.h>

#define NU 50000
#define NE 100000
#define DIM 64
#define NRELS 16
#define EKG 1500000
#define EIN 1000000

#define KG_CHUNK 8192
#define KG_NBUCK ((NE + 511) >> 9)   // 196
#define B8_CHUNK 4096
#define KG_CAP 9216                  // Binomial mean 7680, sigma 87 -> +17s
#define C8_CAP 6656                  // mean 5120, sigma 71 -> +21s

#define NEB (NE / 4)                 // 25000 ent blocks
#define NUB (NU / 4)                 // 12500 usr blocks

#define NB_BKG ((EKG + KG_CHUNK - 1) / KG_CHUNK)   // 184
#define NB_B8  ((EIN + B8_CHUNK - 1) / B8_CHUNK)   // 245
#define NB_CKG KG_NBUCK                             // 196
#define NB_CUI ((NU + 255) >> 8)                    // 196
#define NB_CIU ((NE + 511) >> 9)                    // 196

typedef _Float16 f16x2 __attribute__((ext_vector_type(2)));

union U16 { int4 v; __half2 h[4]; };
union H4 { int2 i2; __half2 h[2]; };

__device__ __forceinline__ float fdot2a(__half2 a, __half2 b, float c) {
#if __has_builtin(__builtin_amdgcn_fdot2)
    union { __half2 h; f16x2 v; } ua, ub;
    ua.h = a; ub.h = b;
    return __builtin_amdgcn_fdot2(ua.v, ub.v, c, false);
#else
    return c + __half2float(a.x) * __half2float(b.x) + __half2float(a.y) * __half2float(b.y);
#endif
}

// sum over each 4-lane quad via DPP (score reduce; head = quad)
__device__ __forceinline__ float dpp_red4(float p) {
    int t;
    t = __builtin_amdgcn_update_dpp(0, __float_as_int(p), 0xB1, 0xF, 0xF, true);  // quad_perm xor1
    p += __int_as_float(t);
    t = __builtin_amdgcn_update_dpp(0, __float_as_int(p), 0x4E, 0xF, 0xF, true);  // quad_perm xor2
    p += __int_as_float(t);
    return p;
}

// fp16 mirror cast for usr + rel (ent cast folded into k_gemm_f)
__global__ void k_castH(const float4* __restrict__ u4, const float4* __restrict__ r4,
                        int2* __restrict__ uH, int2* __restrict__ rH) {
    int i = blockIdx.x * blockDim.x + threadIdx.x;
    if (i < NU * 16) {
        float4 v = u4[i];
        H4 o; o.h[0] = __floats2half2_rn(v.x, v.y); o.h[1] = __floats2half2_rn(v.z, v.w);
        uH[i] = o.i2;
    }
    if (i < NRELS * 16) {
        float4 v = r4[i];
        H4 o; o.h[0] = __floats2half2_rn(v.x, v.y); o.h[1] = __floats2half2_rn(v.z, v.w);
        rH[i] = o.i2;
    }
}

// qe record per node = 256B: halfs [0..63] = qm row, [64..127] = ent row.
// k_gemm_f: computes qm = ent0 @ WQ -> qe.qm, AND casts ent0 -> qe.ent.
__global__ __launch_bounds__(256) void k_gemm_f(const float* __restrict__ ent,
                                                const float* __restrict__ wq,
                                                int2* __restrict__ qe) {
    __shared__ float sW[64 * 64];
    __shared__ float sR[16 * 64];
    int t = threadIdx.x;
    for (int i = t; i < 4096; i += 256) sW[i] = wq[i];
    long row0 = (long)blockIdx.x * 16;
    for (int i = t; i < 1024; i += 256) sR[i] = ent[row0 * 64 + i];
    __syncthreads();
    int r = t >> 4, cg = t & 15;
    const float4* sW4 = (const float4*)sW;
    const float4* sR4 = (const float4*)sR;
    float4 acc = {0.f, 0.f, 0.f, 0.f};
#pragma unroll
    for (int k = 0; k < 64; k++) {
        float a = sR[r * 64 + k];
        float4 wv = sW4[k * 16 + cg];
        acc.x += a * wv.x; acc.y += a * wv.y; acc.z += a * wv.z; acc.w += a * wv.w;
    }
    long rec = (row0 + r) * 32;     // record = 32 int2
    H4 o;
    o.h[0] = __floats2half2_rn(acc.x, acc.y);
    o.h[1] = __floats2half2_rn(acc.z, acc.w);
    qe[rec + cg] = o.i2;
    float4 ev = sR4[r * 16 + cg];
    H4 e;
    e.h[0] = __floats2half2_rn(ev.x, ev.y);
    e.h[1] = __floats2half2_rn(ev.z, ev.w);
    qe[rec + 16 + cg] = e.i2;
}

// layer-1 gemm: reads fp16 ent rows from qe_b.ent, writes qm into qe_b.qm
__global__ __launch_bounds__(256) void k_gemm_h(const float* __restrict__ wq,
                                                int2* __restrict__ qe) {
    __shared__ float sW[64 * 64];
    __shared__ float sR[16 * 64];
    int t = threadIdx.x;
    for (int i = t; i < 4096; i += 256) sW[i] = wq[i];
    long row0 = (long)blockIdx.x * 16;
    const __half2* e2 = (const __half2*)qe;   // record = 128 halfs = 64 half2
    for (int i = t; i < 512; i += 256) {
        int rr = i >> 5, j = i & 31;
        float2 f = __half22float2(e2[(row0 + rr) * 64 + 32 + j]);
        sR[rr * 64 + 2 * j] = f.x; sR[rr * 64 + 2 * j + 1] = f.y;
    }
    __syncthreads();
    int r = t >> 4, cg = t & 15;
    const float4* sW4 = (const float4*)sW;
    float4 acc = {0.f, 0.f, 0.f, 0.f};
#pragma unroll
    for (int k = 0; k < 64; k++) {
        float a = sR[r * 64 + k];
        float4 wv = sW4[k * 16 + cg];
        acc.x += a * wv.x; acc.y += a * wv.y; acc.z += a * wv.z; acc.w += a * wv.w;
    }
    H4 o;
    o.h[0] = __floats2half2_rn(acc.x, acc.y);
    o.h[1] = __floats2half2_rn(acc.z, acc.w);
    qe[(row0 + r) * 32 + cg] = o.i2;
}

// ---- bucket-level histogram (LDS-privatized) ----
__global__ __launch_bounds__(256) void k_hist_bucket(const int* __restrict__ eh,
        const int* __restrict__ iu, const int* __restrict__ ii,
        int* __restrict__ cntK, int* __restrict__ cntU, int* __restrict__ cntI) {
    __shared__ int sK[256], sU[256], sI[256];
    int t = threadIdx.x;
    sK[t] = 0; sU[t] = 0; sI[t] = 0;
    __syncthreads();
    int stride = gridDim.x * 256;
    for (int e = blockIdx.x * 256 + t; e < EKG; e += stride)
        atomicAdd(&sK[eh[e] >> 9], 1);
    for (int e = blockIdx.x * 256 + t; e < EIN; e += stride) {
        atomicAdd(&sU[iu[e] >> 8], 1);
        atomicAdd(&sI[ii[e] >> 9], 1);
    }
    __syncthreads();
    if (sK[t]) atomicAdd(&cntK[t], sK[t]);
    if (sU[t]) atomicAdd(&cntU[t], sU[t]);
    if (sI[t]) atomicAdd(&cntI[t], sI[t]);
}

// ---- tiny scans: bucket counts -> bucket offsets + gcur init ----
__global__ __launch_bounds__(256) void k_bucket_scan(const int* __restrict__ cntK,
        const int* __restrict__ cntU, const int* __restrict__ cntI,
        int* __restrict__ kg_boff, int* __restrict__ ui_boff, int* __restrict__ iu_boff,
        int* __restrict__ kg_g, int* __restrict__ ui_g, int* __restrict__ iu_g) {
    __shared__ int sc[256];
    int t = threadIdx.x;
#define SCAN1(cnt, boff, gcur) { \
    int v = cnt[t]; sc[t] = v; __syncthreads(); \
    for (int o = 1; o < 256; o <<= 1) { \
        int u = (t >= o) ? sc[t - o] : 0; __syncthreads(); sc[t] += u; __syncthreads(); } \
    int e = sc[t] - v; boff[t] = e; gcur[t] = e; \
    __syncthreads(); }
    SCAN1(cntK, kg_boff, kg_g)
    SCAN1(cntU, ui_boff, ui_g)
    SCAN1(cntI, iu_boff, iu_g)
#undef SCAN1
}

// ---- merged pass B ----
struct SmB {
    union {
        struct { unsigned stage[KG_CHUNK]; int dest[KG_CHUNK]; } kg;
        struct { int2 stage[B8_CHUNK]; int dest[B8_CHUNK]; } b8;
    } u;
};

__device__ __forceinline__ void binB8_body(const int* __restrict__ key,
        const int* __restrict__ aux, const float* __restrict__ wv, int nE,
        int shift, int auxShift, int* __restrict__ gcur, int2* __restrict__ tmp,
        int cb, int2* stage, int* dest,
        int* cnt, int* boff, int* gbase, int* curl, int* sc) {
    int t = threadIdx.x;
    int base = cb * B8_CHUNK;
    int nloc = nE - base; if (nloc > B8_CHUNK) nloc = B8_CHUNK;
    cnt[t] = 0;
    __syncthreads();
    for (int i = t; i < nloc; i += 256)
        atomicAdd(&cnt[key[base + i] >> shift], 1);
    __syncthreads();
    int v = cnt[t];
    sc[t] = v;
    __syncthreads();
    for (int o = 1; o < 256; o <<= 1) {
        int u = (t >= o) ? sc[t - o] : 0;
        __syncthreads();
        sc[t] += u;
        __syncthreads();
    }
    boff[t] = sc[t] - v;
    curl[t] = sc[t] - v;
    gbase[t] = atomicAdd(&gcur[t], v);
    __syncthreads();
    int lowmask = (1 << shift) - 1;
    for (int i = t; i < nloc; i += 256) {
        int e = base + i;
        int k = key[e];
        int b = k >> shift;
        int2 pay;
        pay.x = aux[e] | ((k & lowmask) << auxShift);
        pay.y = __float_as_int(wv[e]);
        int pos = atomicAdd(&curl[b], 1);
        stage[pos] = pay;
        dest[pos] = gbase[b] + (pos - boff[b]);
    }
    __syncthreads();
    for (int s = t; s < nloc; s += 256) tmp[dest[s]] = stage[s];
}

__global__ __launch_bounds__(256) void k_binB_all(const int* __restrict__ eh,
        const int* __restrict__ et, const int* __restrict__ ety,
        int* __restrict__ kg_g, unsigned* __restrict__ kg_tmp,
        const int* __restrict__ iu, const int* __restrict__ ii,
        const float* __restrict__ iwf,
        int* __restrict__ ui_g, int2* __restrict__ ui_tmp,
        int* __restrict__ iu_g, int2* __restrict__ iu_tmp) {
    __shared__ SmB sm;
    __shared__ int cnt[256], boff[256], gbase[256], curl[256], sc[256];
    int bid = blockIdx.x;
    int t = threadIdx.x;
    if (bid < NB_BKG) {
        int base = bid * KG_CHUNK;
        int nloc = EKG - base; if (nloc > KG_CHUNK) nloc = KG_CHUNK;
        for (int i = t; i < KG_NBUCK; i += 256) cnt[i] = 0;
        __syncthreads();
        for (int i = t; i < nloc; i += 256)
            atomicAdd(&cnt[eh[base + i] >> 9], 1);
        __syncthreads();
        int v = (t < KG_NBUCK) ? cnt[t] : 0;
        sc[t] = v;
        __syncthreads();
        for (int o = 1; o < 256; o <<= 1) {
            int u = (t >= o) ? sc[t - o] : 0;
            __syncthreads();
            sc[t] += u;
            __syncthreads();
        }
        if (t < KG_NBUCK) {
            boff[t] = sc[t] - v;
            curl[t] = sc[t] - v;
            gbase[t] = atomicAdd(&kg_g[t], v);
        }
        __syncthreads();
        for (int i = t; i < nloc; i += 256) {
            int e = base + i;
            int h = eh[e];
            int b = h >> 9;
            unsigned pay = (unsigned)et[e] | ((unsigned)(ety[e] - 1) << 17)
                         | ((unsigned)(h & 511) << 21);
            int pos = atomicAdd(&curl[b], 1);
            sm.u.kg.stage[pos] = pay;
            sm.u.kg.dest[pos] = gbase[b] + (pos - boff[b]);
        }
        __syncthreads();
        for (int s = t; s < nloc; s += 256) kg_tmp[sm.u.kg.dest[s]] = sm.u.kg.stage[s];
    } else if (bid < NB_BKG + NB_B8) {
        binB8_body(iu, ii, iwf, EIN, 8, 17, ui_g, ui_tmp, bid - NB_BKG,
                   sm.u.b8.stage, sm.u.b8.dest, cnt, boff, gbase, curl, sc);
    } else {
        binB8_body(ii, iu, iwf, EIN, 9, 16, iu_g, iu_tmp, bid - NB_BKG - NB_B8,
                   sm.u.b8.stage, sm.u.b8.dest, cnt, boff, gbase, curl, sc);
    }
}

// ---- merged pass C ----
struct SmC {
    union {
        unsigned kgstage[KG_CAP];
        int2 c8stage[C8_CAP];
    } u;
};

__device__ __forceinline__ void binC8_body(const int2* __restrict__ tmp,
        const int* __restrict__ boffg, int2* __restrict__ dst, int* __restrict__ off,
        int nnodes, int shift, int auxShift, int lb, int nb,
        int2* stage, int* curl, int* sc) {
    int b = lb;
    int nbase = b << shift;
    int nlim = nnodes - nbase; if (nlim > (1 << shift)) nlim = 1 << shift;
    if (nlim <= 0) return;
    int t = threadIdx.x;
    int r0 = boffg[b];
    int r1 = boffg[b + 1];
    int cntb = r1 - r0;
    int lowmask = (1 << shift) - 1;
    curl[t] = 0; curl[t + 256] = 0;
    __syncthreads();
    for (int s = t; s < cntb; s += 256)
        atomicAdd(&curl[(tmp[r0 + s].x >> auxShift) & lowmask], 1);
    __syncthreads();
    int v0 = curl[2 * t], v1 = curl[2 * t + 1];
    int s2 = v0 + v1;
    sc[t] = s2;
    __syncthreads();
    for (int o = 1; o < 256; o <<= 1) {
        int u = (t >= o) ? sc[t - o] : 0;
        __syncthreads();
        sc[t] += u;
        __syncthreads();
    }
    int excl = sc[t] - s2;
    curl[2 * t] = excl;
    curl[2 * t + 1] = excl + v0;
    if (2 * t < nlim) off[nbase + 2 * t] = r0 + excl;
    if (2 * t + 1 < nlim) off[nbase + 2 * t + 1] = r0 + excl + v0;
    if (b == nb - 1 && t == 0) off[nbase + nlim] = r1;  // sentinel
    __syncthreads();
    if (cntb <= C8_CAP) {
        for (int s = t; s < cntb; s += 256) {
            int2 pay = tmp[r0 + s];
            int l = (pay.x >> auxShift) & lowmask;
            int pos = atomicAdd(&curl[l], 1);
            stage[pos] = pay;
        }
        __syncthreads();
        for (int s = t; s < cntb; s += 256) dst[r0 + s] = stage[s];
    } else {
        for (int s = t; s < cntb; s += 256) {
            int2 pay = tmp[r0 + s];
            int l = (pay.x >> auxShift) & lowmask;
            int pos = atomicAdd(&curl[l], 1);
            dst[r0 + pos] = pay;
        }
    }
}

__global__ __launch_bounds__(256) void k_binC_all(const unsigned* __restrict__ kg_tmp,
        const int* __restrict__ kg_boff, unsigned* __restrict__ kg_tr, int* __restrict__ kg_off,
        const int2* __restrict__ ui_tmp, const int* __restrict__ ui_boff,
        int2* __restrict__ ui_iw, int* __restrict__ ui_off,
        const int2* __restrict__ iu_tmp, const int* __restrict__ iu_boff,
        int2* __restrict__ iu_iw, int* __restrict__ iu_off) {
    __shared__ SmC sm;
    __shared__ int curl[512];
    __shared__ int sc[256];
    int bid = blockIdx.x;
    int t = threadIdx.x;
    if (bid < NB_CKG) {
        int b = bid;
        int nbase = b << 9;
        int nlim = NE - nbase; if (nlim > 512) nlim = 512;
        if (nlim <= 0) return;
        int r0 = kg_boff[b];
        int r1 = kg_boff[b + 1];
        int cntb = r1 - r0;
        curl[t] = 0; curl[t + 256] = 0;
        __syncthreads();
        for (int s = t; s < cntb; s += 256)
            atomicAdd(&curl[(kg_tmp[r0 + s] >> 21) & 511], 1);
        __syncthreads();
        int v0 = curl[2 * t], v1 = curl[2 * t + 1];
        int s2 = v0 + v1;
        sc[t] = s2;
        __syncthreads();
        for (int o = 1; o < 256; o <<= 1) {
            int u = (t >= o) ? sc[t - o] : 0;
            __syncthreads();
            sc[t] += u;
            __syncthreads();
        }
        int excl = sc[t] - s2;
        curl[2 * t] = excl;
        curl[2 * t + 1] = excl + v0;
        if (2 * t < nlim) kg_off[nbase + 2 * t] = r0 + excl;
        if (2 * t + 1 < nlim) kg_off[nbase + 2 * t + 1] = r0 + excl + v0;
        if (b == NB_CKG - 1 && t == 0) kg_off[nbase + nlim] = r1;   // sentinel off[NE]
        __syncthreads();
        if (cntb <= KG_CAP) {
            for (int s = t; s < cntb; s += 256) {
                unsigned pay = kg_tmp[r0 + s];
                int l = (pay >> 21) & 511;
                int pos = atomicAdd(&curl[l], 1);
                sm.u.kgstage[pos] = pay;
            }
            __syncthreads();
            for (int s = t; s < cntb; s += 256) kg_tr[r0 + s] = sm.u.kgstage[s];
        } else {
            for (int s = t; s < cntb; s += 256) {
                unsigned pay = kg_tmp[r0 + s];
                int l = (pay >> 21) & 511;
                int pos = atomicAdd(&curl[l], 1);
                kg_tr[r0 + pos] = pay;
            }
        }
    } else if (bid < NB_CKG + NB_CUI) {
        binC8_body(ui_tmp, ui_boff, ui_iw, ui_off, NU, 8, 17,
                   bid - NB_CKG, NB_CUI, sm.u.c8stage, curl, sc);
    } else {
        binC8_body(iu_tmp, iu_boff, iu_iw, iu_off, NE, 9, 16,
                   bid - NB_CKG - NB_CUI, NB_CIU, sm.u.c8stage, curl, sc);
    }
}

// ---- fused per-layer kernel. qe = interleaved 256B records {qm_row, ent_row}.
// Inner-loop arithmetic bit-identical to R6; only gather addressing changed.
// FIRST=true: eacc/uacc stores (no RMW; buffers start undefined, not zeroed).
// FINAL=true: folds k_final epilogue, skips fp16/acc write-backs.
template<bool FIRST, bool FINAL>
__global__ __launch_bounds__(256) void k_layer(const int4* __restrict__ qe,
        const __half* __restrict__ relH, const __half* __restrict__ usrH,
        const int* __restrict__ kg_off, const unsigned* __restrict__ kg_tr,
        const int* __restrict__ iu_off, const int2* __restrict__ iu_iw,
        const int* __restrict__ ui_off, const int2* __restrict__ ui_iw,
        float* __restrict__ eacc, int4* __restrict__ qe_out,
        float* __restrict__ uacc, __half* __restrict__ usrHout,
        const float* __restrict__ ent0, const float* __restrict__ usr0,
        float* __restrict__ out) {
    int w = __builtin_amdgcn_readfirstlane(threadIdx.x >> 6);
    int lane = threadIdx.x & 63;
    int sub = lane >> 3;          // edge slot 0..7
    int li  = lane & 7;           // dims 8li..8li+7
    const float SC = 0.17677669529663687f; // 1/sqrt(32)
    const float NEG = -1e30f;
    const float inv3 = 1.f / 3.f;
    const int4* relI = (const int4*)relH;
    const int4* usrI = (const int4*)usrH;

    if (blockIdx.x < NEB) {
        // ================= entity path =================
        int node = blockIdx.x * 4 + w;
        U16 qh; qh.v = qe[(long)node * 16 + li];
        int b0 = kg_off[node], b1 = kg_off[node + 1];
        int deg = b1 - b0;

        float ssum = 0.f;
        float acc[8] = {0.f, 0.f, 0.f, 0.f, 0.f, 0.f, 0.f, 0.f};
        if (deg > 0) {
            int s = b0;
            int i0 = s + sub;
            unsigned tr = kg_tr[i0 < b1 ? i0 : b1 - 1];
            for (; s < b1; s += 8) {
                int ni = s + 8 + sub;
                unsigned trn = kg_tr[ni < b1 ? ni : b1 - 1];  // prefetch next step's payload
                bool has = (s + sub) < b1;
                int tl = tr & 0x1FFFF, rr = (tr >> 17) & 15;
                U16 rl; rl.v = relI[rr * 8 + li];
                long rec = (long)tl * 16;
                U16 qt; qt.v = qe[rec + li];          // qm half of record
                U16 ev; ev.v = qe[rec + 8 + li];      // ent half (adjacent 128B line)
                float p = 0.f;
#pragma unroll
                for (int k = 0; k < 4; k++) {
                    __half2 kk = __hmul2(qt.h[k], rl.h[k]);
                    p = fdot2a(qh.h[k], kk, p);
                }
                p = dpp_red4(p);
                float e = __expf(has ? p * SC : NEG);
                ssum += e;
#pragma unroll
                for (int k = 0; k < 4; k++) {
                    __half2 v2 = __hmul2(ev.h[k], rl.h[k]);
                    float2 vf = __half22float2(v2);
                    acc[2 * k]     += vf.x * e;
                    acc[2 * k + 1] += vf.y * e;
                }
                tr = trn;
            }
#pragma unroll
            for (int o = 8; o <= 32; o <<= 1) {
                ssum += __shfl_xor(ssum, o, 64);
#pragma unroll
                for (int k = 0; k < 8; k++) acc[k] += __shfl_xor(acc[k], o, 64);
            }
            float inv = 1.f / ssum;
#pragma unroll
            for (int k = 0; k < 8; k++) acc[k] *= inv;
            float ss = 0.f;
#pragma unroll
            for (int k = 0; k < 8; k++) ss += acc[k] * acc[k];
            ss += __shfl_xor(ss, 1, 64);
            ss += __shfl_xor(ss, 2, 64);
            ss += __shfl_xor(ss, 4, 64);
            float nsc = 1.f / fmaxf(sqrtf(ss), 1e-12f);
#pragma unroll
            for (int k = 0; k < 8; k++) acc[k] *= nsc;
        }

        // user -> entity gather
        int c0 = iu_off[node], c1 = iu_off[node + 1];
        if (c1 > c0) {
            float ua[8] = {0.f, 0.f, 0.f, 0.f, 0.f, 0.f, 0.f, 0.f};
            int t2 = c0;
            int j0 = t2 + sub;
            int2 pw = iu_iw[j0 < c1 ? j0 : c1 - 1];
            for (; t2 < c1; t2 += 8) {
                int nj = t2 + 8 + sub;
                int2 pwn = iu_iw[nj < c1 ? nj : c1 - 1];
                bool has = (t2 + sub) < c1;
                float wv = has ? __int_as_float(pw.y) : 0.f;
                U16 uu; uu.v = usrI[(long)(pw.x & 0xFFFF) * 8 + li];
#pragma unroll
                for (int k = 0; k < 4; k++) {
                    float2 uf = __half22float2(uu.h[k]);
                    ua[2 * k]     += wv * uf.x;
                    ua[2 * k + 1] += wv * uf.y;
                }
                pw = pwn;
            }
#pragma unroll
            for (int o = 8; o <= 32; o <<= 1) {
#pragma unroll
                for (int k = 0; k < 8; k++) ua[k] += __shfl_xor(ua[k], o, 64);
            }
#pragma unroll
            for (int k = 0; k < 8; k++) acc[k] += ua[k];
        }

        if (sub == 0) {
            long base = (long)node * 16 + 2 * li;
            float4* eacc4 = (float4*)eacc;
            float4 e0, e1;
            if (FIRST) {
                e0.x = acc[0]; e0.y = acc[1]; e0.z = acc[2]; e0.w = acc[3];
                e1.x = acc[4]; e1.y = acc[5]; e1.z = acc[6]; e1.w = acc[7];
            } else {
                e0 = eacc4[base]; e1 = eacc4[base + 1];
                e0.x += acc[0]; e0.y += acc[1]; e0.z += acc[2]; e0.w += acc[3];
                e1.x += acc[4]; e1.y += acc[5]; e1.z += acc[6]; e1.w += acc[7];
            }
            if (!FINAL) {
                eacc4[base] = e0; eacc4[base + 1] = e1;
                U16 ho;
                ho.h[0] = __floats2half2_rn(acc[0], acc[1]);
                ho.h[1] = __floats2half2_rn(acc[2], acc[3]);
                ho.h[2] = __floats2half2_rn(acc[4], acc[5]);
                ho.h[3] = __floats2half2_rn(acc[6], acc[7]);
                qe_out[(long)node * 16 + 8 + li] = ho.v;   // ent half of next record
            } else {
                const float4* a4 = (const float4*)ent0;
                float4 a0 = a4[base], a1 = a4[base + 1];
                float4 o0, o1;
                o0.x = (a0.x + e0.x) * inv3; o0.y = (a0.y + e0.y) * inv3;
                o0.z = (a0.z + e0.z) * inv3; o0.w = (a0.w + e0.w) * inv3;
                o1.x = (a1.x + e1.x) * inv3; o1.y = (a1.y + e1.y) * inv3;
                o1.z = (a1.z + e1.z) * inv3; o1.w = (a1.w + e1.w) * inv3;
                float4* oute = (float4*)out + (long)NU * 16;
                oute[base] = o0; oute[base + 1] = o1;
            }
        }
    } else {
        // ================= user path =================
        int node = (blockIdx.x - NEB) * 4 + w;
        int b0 = ui_off[node], b1 = ui_off[node + 1];
        float ax[8] = {0.f, 0.f, 0.f, 0.f, 0.f, 0.f, 0.f, 0.f};
        if (b1 > b0) {
            int s = b0;
            int j0 = s + sub;
            int2 pw = ui_iw[j0 < b1 ? j0 : b1 - 1];
            for (; s < b1; s += 8) {
                int nj = s + 8 + sub;
                int2 pwn = ui_iw[nj < b1 ? nj : b1 - 1];
                bool has = (s + sub) < b1;
                float wv = has ? __int_as_float(pw.y) : 0.f;
                U16 uu; uu.v = qe[(long)(pw.x & 0x1FFFF) * 16 + 8 + li];  // ent half
#pragma unroll
                for (int k = 0; k < 4; k++) {
                    float2 uf = __half22float2(uu.h[k]);
                    ax[2 * k]     += wv * uf.x;
                    ax[2 * k + 1] += wv * uf.y;
                }
                pw = pwn;
            }
#pragma unroll
            for (int o = 8; o <= 32; o <<= 1) {
#pragma unroll
                for (int k = 0; k < 8; k++) ax[k] += __shfl_xor(ax[k], o, 64);
            }
        }
        if (sub == 0) {
            long base = (long)node * 16 + 2 * li;
            float4* uacc4 = (float4*)uacc;
            float4 u0, u1;
            if (FIRST) {
                u0.x = ax[0]; u0.y = ax[1]; u0.z = ax[2]; u0.w = ax[3];
                u1.x = ax[4]; u1.y = ax[5]; u1.z = ax[6]; u1.w = ax[7];
            } else {
                u0 = uacc4[base]; u1 = uacc4[base + 1];
                u0.x += ax[0]; u0.y += ax[1]; u0.z += ax[2]; u0.w += ax[3];
                u1.x += ax[4]; u1.y += ax[5]; u1.z += ax[6]; u1.w += ax[7];
            }
            if (!FINAL) {
                uacc4[base] = u0; uacc4[base + 1] = u1;
                U16 ho;
                ho.h[0] = __floats2half2_rn(ax[0], ax[1]);
                ho.h[1] = __floats2half2_rn(ax[2], ax[3]);
                ho.h[2] = __floats2half2_rn(ax[4], ax[5]);
                ho.h[3] = __floats2half2_rn(ax[6], ax[7]);
                ((int4*)usrHout)[(long)node * 8 + li] = ho.v;
            } else {
                const float4* a4 = (const float4*)usr0;
                float4 a0 = a4[base], a1 = a4[base + 1];
                float4 o0, o1;
                o0.x = (a0.x + u0.x) * inv3; o0.y = (a0.y + u0.y) * inv3;
                o0.z = (a0.z + u0.z) * inv3; o0.w = (a0.w + u0.w) * inv3;
                o1.x = (a1.x + u1.x) * inv3; o1.y = (a1.y + u1.y) * inv3;
                o1.z = (a1.z + u1.z) * inv3; o1.w = (a1.w + u1.w) * inv3;
                float4* outu = (float4*)out;
                outu[base] = o0; outu[base + 1] = o1;
            }
        }
    }
}

extern "C" void kernel_launch(void* const* d_in, const int* in_sizes, int n_in,
                              void* d_out, int out_size, void* d_ws, size_t ws_size,
                              hipStream_t stream) {
    const float* usr0  = (const float*)d_in[1];
    const float* ent0  = (const float*)d_in[2];
    const int*   inter = (const int*)d_in[3];
    const float* iwf   = (const float*)d_in[4];
    const int*   eidx  = (const int*)d_in[5];
    const int*   etype = (const int*)d_in[6];
    const float* relf  = (const float*)d_in[7];
    const float* wqf   = (const float*)d_in[8];
    float* out = (float*)d_out;

    const int* eh = eidx;
    const int* et = eidx + EKG;
    const int* iu = inter;
    const int* ii = inter + EIN;

    // ---- workspace layout (4B words) ----
    float* p = (float*)d_ws;
    float* eacc = p;  p += (long)NE * DIM;
    float* uacc = p;  p += (long)NU * DIM;
    int4* qe_a  = (int4*)p;  p += (long)NE * 64;          // 256B records {qm,ent}, 25.6MB
    __half* usrHa = (__half*)p;  p += (long)NU * DIM / 2;
    __half* usrHb = (__half*)p;  p += (long)NU * DIM / 2;
    __half* relH  = (__half*)p;  p += (long)NRELS * DIM / 2;
    int* cntK = (int*)p;        p += 256;
    int* cntU = (int*)p;        p += 256;
    int* cntI = (int*)p;        p += 256;
    int* kg_boff = (int*)p;     p += 256;
    int* ui_boff = (int*)p;     p += 256;
    int* iu_boff = (int*)p;     p += 256;
    int* kg_off = (int*)p;      p += NE + 2;
    int* ui_off = (int*)p;      p += NU + 2;
    int* iu_off = (int*)p;      p += NE + 2;
    int* kg_g   = (int*)p;      p += 256;
    int* ui_g   = (int*)p;      p += 256;
    int* iu_g   = (int*)p;      p += 256;
    unsigned* kg_tr  = (unsigned*)p; p += EKG;
    int2* ui_iw  = (int2*)p;    p += (long)EIN * 2;
    int2* iu_iw  = (int2*)p;    p += (long)EIN * 2;
    // UNION region: {kg_tmp, ui_tmp, iu_tmp} (binning scratch, dead after binC)
    // aliased with qe_b (written only after binC completes).
    char* uni = (char*)p;
    unsigned* kg_tmp = (unsigned*)uni;                       // 6MB
    int2* ui_tmp = (int2*)(uni + (size_t)EKG * 4);           // 8MB
    int2* iu_tmp = (int2*)(uni + (size_t)EKG * 4 + (size_t)EIN * 8);
    int4* qe_b = (int4*)uni;                                 // 25.6MB (>= 22MB scratch)

    const int B = 256;

    // ---- init: bucket counters only (eacc/uacc written in store-mode) ----
    hipMemsetAsync(cntK, 0, (size_t)768 * 4, stream);
    k_castH<<<(NU * 16 + B - 1) / B, B, 0, stream>>>((const float4*)usr0, (const float4*)relf,
                                                     (int2*)usrHa, (int2*)relH);

    // ---- CSR build ----
    k_hist_bucket<<<512, 256, 0, stream>>>(eh, iu, ii, cntK, cntU, cntI);
    k_bucket_scan<<<1, 256, 0, stream>>>(cntK, cntU, cntI, kg_boff, ui_boff, iu_boff,
                                         kg_g, ui_g, iu_g);
    k_binB_all<<<NB_BKG + NB_B8 + NB_B8, 256, 0, stream>>>(eh, et, etype, kg_g, kg_tmp,
                                                           iu, ii, iwf,
                                                           ui_g, ui_tmp, iu_g, iu_tmp);
    k_binC_all<<<NB_CKG + NB_CUI + NB_CIU, 256, 0, stream>>>(kg_tmp, kg_boff, kg_tr, kg_off,
                                                             ui_tmp, ui_boff, ui_iw, ui_off,
                                                             iu_tmp, iu_boff, iu_iw, iu_off);

    // ---- layer 0 ----
    k_gemm_f<<<NE / 16, 256, 0, stream>>>(ent0, wqf, (int2*)qe_a);
    k_layer<true, false><<<NEB + NUB, 256, 0, stream>>>(qe_a, relH, usrHa,
                                                        kg_off, kg_tr, iu_off, iu_iw,
                                                        ui_off, ui_iw,
                                                        eacc, qe_b, uacc, usrHb,
                                                        nullptr, nullptr, nullptr);
    // ---- layer 1 (folds k_final) ----
    k_gemm_h<<<NE / 16, 256, 0, stream>>>(wqf, (int2*)qe_b);
    k_layer<false, true><<<NEB + NUB, 256, 0, stream>>>(qe_b, relH, usrHb,
                                                        kg_off, kg_tr, iu_off, iu_iw,
                                                        ui_off, ui_iw,
                                                        eacc, nullptr, uacc, nullptr,
                                                        ent0, usr0, out);
}

// Round 8
// 498.085 us; speedup vs baseline: 1.0185x; 1.0185x over previous
//
#include <hip/hip_runtime.h>
#include <hip/hip_fp16.h>

#define NU 50000
#define NE 100000
#define DIM 64
#define NRELS 16
#define EKG 1500000
#define EIN 1000000

#define KG_CHUNK 8192
#define KG_NBUCK ((NE + 511) >> 9)   // 196
#define B8_CHUNK 4096
#define KG_CAP 9216                  // Binomial mean 7680, sigma 87 -> +17s
#define C8_CAP 6656                  // mean 5120, sigma 71 -> +21s

#define NEB (NE / 4)                 // 25000 ent blocks
#define NUB (NU / 4)                 // 12500 usr blocks

#define NB_BKG ((EKG + KG_CHUNK - 1) / KG_CHUNK)   // 184
#define NB_B8  ((EIN + B8_CHUNK - 1) / B8_CHUNK)   // 245
#define NB_CKG KG_NBUCK                             // 196
#define NB_CUI ((NU + 255) >> 8)                    // 196
#define NB_CIU ((NE + 511) >> 9)                    // 196

typedef _Float16 f16x2 __attribute__((ext_vector_type(2)));

union U16 { int4 v; __half2 h[4]; };
union H4 { int2 i2; __half2 h[2]; };
union LI { long long l; int2 v; };

__device__ __forceinline__ unsigned ntld_u(const unsigned* p) {
    return __builtin_nontemporal_load(p);
}
__device__ __forceinline__ int2 ntld_i2(const int2* p) {
    LI u; u.l = __builtin_nontemporal_load((const long long*)p); return u.v;
}

__device__ __forceinline__ float fdot2a(__half2 a, __half2 b, float c) {
#if __has_builtin(__builtin_amdgcn_fdot2)
    union { __half2 h; f16x2 v; } ua, ub;
    ua.h = a; ub.h = b;
    return __builtin_amdgcn_fdot2(ua.v, ub.v, c, false);
#else
    return c + __half2float(a.x) * __half2float(b.x) + __half2float(a.y) * __half2float(b.y);
#endif
}

// sum over each 4-lane quad via DPP (score reduce; head = quad)
__device__ __forceinline__ float dpp_red4(float p) {
    int t;
    t = __builtin_amdgcn_update_dpp(0, __float_as_int(p), 0xB1, 0xF, 0xF, true);  // quad_perm xor1
    p += __int_as_float(t);
    t = __builtin_amdgcn_update_dpp(0, __float_as_int(p), 0x4E, 0xF, 0xF, true);  // quad_perm xor2
    p += __int_as_float(t);
    return p;
}

// fp16 mirror cast for usr + rel (ent cast folded into k_gemm_f)
__global__ void k_castH(const float4* __restrict__ u4, const float4* __restrict__ r4,
                        int2* __restrict__ uH, int2* __restrict__ rH) {
    int i = blockIdx.x * blockDim.x + threadIdx.x;
    if (i < NU * 16) {
        float4 v = u4[i];
        H4 o; o.h[0] = __floats2half2_rn(v.x, v.y); o.h[1] = __floats2half2_rn(v.z, v.w);
        uH[i] = o.i2;
    }
    if (i < NRELS * 16) {
        float4 v = r4[i];
        H4 o; o.h[0] = __floats2half2_rn(v.x, v.y); o.h[1] = __floats2half2_rn(v.z, v.w);
        rH[i] = o.i2;
    }
}

// qm = ent0 @ WQ -> fp16; ALSO casts ent0 -> entH (rows already staged in LDS).
__global__ __launch_bounds__(256) void k_gemm_f(const float* __restrict__ ent,
                                                const float* __restrict__ wq,
                                                __half* __restrict__ qmH,
                                                __half* __restrict__ entH) {
    __shared__ float sW[64 * 64];
    __shared__ float sR[16 * 64];
    int t = threadIdx.x;
    for (int i = t; i < 4096; i += 256) sW[i] = wq[i];
    long row0 = (long)blockIdx.x * 16;
    for (int i = t; i < 1024; i += 256) sR[i] = ent[row0 * 64 + i];
    __syncthreads();
    int r = t >> 4, cg = t & 15;
    const float4* sW4 = (const float4*)sW;
    const float4* sR4 = (const float4*)sR;
    float4 acc = {0.f, 0.f, 0.f, 0.f};
#pragma unroll
    for (int k = 0; k < 64; k++) {
        float a = sR[r * 64 + k];
        float4 wv = sW4[k * 16 + cg];
        acc.x += a * wv.x; acc.y += a * wv.y; acc.z += a * wv.z; acc.w += a * wv.w;
    }
    H4 o;
    o.h[0] = __floats2half2_rn(acc.x, acc.y);
    o.h[1] = __floats2half2_rn(acc.z, acc.w);
    ((int2*)qmH)[(row0 + r) * 16 + cg] = o.i2;
    float4 ev = sR4[r * 16 + cg];
    H4 e;
    e.h[0] = __floats2half2_rn(ev.x, ev.y);
    e.h[1] = __floats2half2_rn(ev.z, ev.w);
    ((int2*)entH)[(row0 + r) * 16 + cg] = e.i2;
}

// layer-1 gemm: fp16 ent input
__global__ __launch_bounds__(256) void k_gemm_h(const __half* __restrict__ ent,
                                                const float* __restrict__ wq,
                                                __half* __restrict__ qmH) {
    __shared__ float sW[64 * 64];
    __shared__ float sR[16 * 64];
    int t = threadIdx.x;
    for (int i = t; i < 4096; i += 256) sW[i] = wq[i];
    long row0 = (long)blockIdx.x * 16;
    const __half2* e2 = (const __half2*)ent;
    for (int i = t; i < 512; i += 256) {
        float2 f = __half22float2(e2[row0 * 32 + i]);
        sR[2 * i] = f.x; sR[2 * i + 1] = f.y;
    }
    __syncthreads();
    int r = t >> 4, cg = t & 15;
    const float4* sW4 = (const float4*)sW;
    float4 acc = {0.f, 0.f, 0.f, 0.f};
#pragma unroll
    for (int k = 0; k < 64; k++) {
        float a = sR[r * 64 + k];
        float4 wv = sW4[k * 16 + cg];
        acc.x += a * wv.x; acc.y += a * wv.y; acc.z += a * wv.z; acc.w += a * wv.w;
    }
    H4 o;
    o.h[0] = __floats2half2_rn(acc.x, acc.y);
    o.h[1] = __floats2half2_rn(acc.z, acc.w);
    ((int2*)qmH)[(row0 + r) * 16 + cg] = o.i2;
}

// ---- bucket-level histogram (LDS-privatized) ----
__global__ __launch_bounds__(256) void k_hist_bucket(const int* __restrict__ eh,
        const int* __restrict__ iu, const int* __restrict__ ii,
        int* __restrict__ cntK, int* __restrict__ cntU, int* __restrict__ cntI) {
    __shared__ int sK[256], sU[256], sI[256];
    int t = threadIdx.x;
    sK[t] = 0; sU[t] = 0; sI[t] = 0;
    __syncthreads();
    int stride = gridDim.x * 256;
    for (int e = blockIdx.x * 256 + t; e < EKG; e += stride)
        atomicAdd(&sK[eh[e] >> 9], 1);
    for (int e = blockIdx.x * 256 + t; e < EIN; e += stride) {
        atomicAdd(&sU[iu[e] >> 8], 1);
        atomicAdd(&sI[ii[e] >> 9], 1);
    }
    __syncthreads();
    if (sK[t]) atomicAdd(&cntK[t], sK[t]);
    if (sU[t]) atomicAdd(&cntU[t], sU[t]);
    if (sI[t]) atomicAdd(&cntI[t], sI[t]);
}

// ---- tiny scans: bucket counts -> bucket offsets + gcur init ----
__global__ __launch_bounds__(256) void k_bucket_scan(const int* __restrict__ cntK,
        const int* __restrict__ cntU, const int* __restrict__ cntI,
        int* __restrict__ kg_boff, int* __restrict__ ui_boff, int* __restrict__ iu_boff,
        int* __restrict__ kg_g, int* __restrict__ ui_g, int* __restrict__ iu_g) {
    __shared__ int sc[256];
    int t = threadIdx.x;
#define SCAN1(cnt, boff, gcur) { \
    int v = cnt[t]; sc[t] = v; __syncthreads(); \
    for (int o = 1; o < 256; o <<= 1) { \
        int u = (t >= o) ? sc[t - o] : 0; __syncthreads(); sc[t] += u; __syncthreads(); } \
    int e = sc[t] - v; boff[t] = e; gcur[t] = e; \
    __syncthreads(); }
    SCAN1(cntK, kg_boff, kg_g)
    SCAN1(cntU, ui_boff, ui_g)
    SCAN1(cntI, iu_boff, iu_g)
#undef SCAN1
}

// ---- merged pass B ----
struct SmB {
    union {
        struct { unsigned stage[KG_CHUNK]; int dest[KG_CHUNK]; } kg;
        struct { int2 stage[B8_CHUNK]; int dest[B8_CHUNK]; } b8;
    } u;
};

__device__ __forceinline__ void binB8_body(const int* __restrict__ key,
        const int* __restrict__ aux, const float* __restrict__ wv, int nE,
        int shift, int auxShift, int* __restrict__ gcur, int2* __restrict__ tmp,
        int cb, int2* stage, int* dest,
        int* cnt, int* boff, int* gbase, int* curl, int* sc) {
    int t = threadIdx.x;
    int base = cb * B8_CHUNK;
    int nloc = nE - base; if (nloc > B8_CHUNK) nloc = B8_CHUNK;
    cnt[t] = 0;
    __syncthreads();
    for (int i = t; i < nloc; i += 256)
        atomicAdd(&cnt[key[base + i] >> shift], 1);
    __syncthreads();
    int v = cnt[t];
    sc[t] = v;
    __syncthreads();
    for (int o = 1; o < 256; o <<= 1) {
        int u = (t >= o) ? sc[t - o] : 0;
        __syncthreads();
        sc[t] += u;
        __syncthreads();
    }
    boff[t] = sc[t] - v;
    curl[t] = sc[t] - v;
    gbase[t] = atomicAdd(&gcur[t], v);
    __syncthreads();
    int lowmask = (1 << shift) - 1;
    for (int i = t; i < nloc; i += 256) {
        int e = base + i;
        int k = key[e];
        int b = k >> shift;
        int2 pay;
        pay.x = aux[e] | ((k & lowmask) << auxShift);
        pay.y = __float_as_int(wv[e]);
        int pos = atomicAdd(&curl[b], 1);
        stage[pos] = pay;
        dest[pos] = gbase[b] + (pos - boff[b]);
    }
    __syncthreads();
    for (int s = t; s < nloc; s += 256) tmp[dest[s]] = stage[s];
}

__global__ __launch_bounds__(256) void k_binB_all(const int* __restrict__ eh,
        const int* __restrict__ et, const int* __restrict__ ety,
        int* __restrict__ kg_g, unsigned* __restrict__ kg_tmp,
        const int* __restrict__ iu, const int* __restrict__ ii,
        const float* __restrict__ iwf,
        int* __restrict__ ui_g, int2* __restrict__ ui_tmp,
        int* __restrict__ iu_g, int2* __restrict__ iu_tmp) {
    __shared__ SmB sm;
    __shared__ int cnt[256], boff[256], gbase[256], curl[256], sc[256];
    int bid = blockIdx.x;
    int t = threadIdx.x;
    if (bid < NB_BKG) {
        int base = bid * KG_CHUNK;
        int nloc = EKG - base; if (nloc > KG_CHUNK) nloc = KG_CHUNK;
        for (int i = t; i < KG_NBUCK; i += 256) cnt[i] = 0;
        __syncthreads();
        for (int i = t; i < nloc; i += 256)
            atomicAdd(&cnt[eh[base + i] >> 9], 1);
        __syncthreads();
        int v = (t < KG_NBUCK) ? cnt[t] : 0;
        sc[t] = v;
        __syncthreads();
        for (int o = 1; o < 256; o <<= 1) {
            int u = (t >= o) ? sc[t - o] : 0;
            __syncthreads();
            sc[t] += u;
            __syncthreads();
        }
        if (t < KG_NBUCK) {
            boff[t] = sc[t] - v;
            curl[t] = sc[t] - v;
            gbase[t] = atomicAdd(&kg_g[t], v);
        }
        __syncthreads();
        for (int i = t; i < nloc; i += 256) {
            int e = base + i;
            int h = eh[e];
            int b = h >> 9;
            unsigned pay = (unsigned)et[e] | ((unsigned)(ety[e] - 1) << 17)
                         | ((unsigned)(h & 511) << 21);
            int pos = atomicAdd(&curl[b], 1);
            sm.u.kg.stage[pos] = pay;
            sm.u.kg.dest[pos] = gbase[b] + (pos - boff[b]);
        }
        __syncthreads();
        for (int s = t; s < nloc; s += 256) kg_tmp[sm.u.kg.dest[s]] = sm.u.kg.stage[s];
    } else if (bid < NB_BKG + NB_B8) {
        binB8_body(iu, ii, iwf, EIN, 8, 17, ui_g, ui_tmp, bid - NB_BKG,
                   sm.u.b8.stage, sm.u.b8.dest, cnt, boff, gbase, curl, sc);
    } else {
        binB8_body(ii, iu, iwf, EIN, 9, 16, iu_g, iu_tmp, bid - NB_BKG - NB_B8,
                   sm.u.b8.stage, sm.u.b8.dest, cnt, boff, gbase, curl, sc);
    }
}

// ---- merged pass C ----
struct SmC {
    union {
        unsigned kgstage[KG_CAP];
        int2 c8stage[C8_CAP];
    } u;
};

__device__ __forceinline__ void binC8_body(const int2* __restrict__ tmp,
        const int* __restrict__ boffg, int2* __restrict__ dst, int* __restrict__ off,
        int nnodes, int shift, int auxShift, int lb, int nb,
        int2* stage, int* curl, int* sc) {
    int b = lb;
    int nbase = b << shift;
    int nlim = nnodes - nbase; if (nlim > (1 << shift)) nlim = 1 << shift;
    if (nlim <= 0) return;
    int t = threadIdx.x;
    int r0 = boffg[b];
    int r1 = boffg[b + 1];
    int cntb = r1 - r0;
    int lowmask = (1 << shift) - 1;
    curl[t] = 0; curl[t + 256] = 0;
    __syncthreads();
    for (int s = t; s < cntb; s += 256)
        atomicAdd(&curl[(tmp[r0 + s].x >> auxShift) & lowmask], 1);
    __syncthreads();
    int v0 = curl[2 * t], v1 = curl[2 * t + 1];
    int s2 = v0 + v1;
    sc[t] = s2;
    __syncthreads();
    for (int o = 1; o < 256; o <<= 1) {
        int u = (t >= o) ? sc[t - o] : 0;
        __syncthreads();
        sc[t] += u;
        __syncthreads();
    }
    int excl = sc[t] - s2;
    curl[2 * t] = excl;
    curl[2 * t + 1] = excl + v0;
    if (2 * t < nlim) off[nbase + 2 * t] = r0 + excl;
    if (2 * t + 1 < nlim) off[nbase + 2 * t + 1] = r0 + excl + v0;
    if (b == nb - 1 && t == 0) off[nbase + nlim] = r1;  // sentinel
    __syncthreads();
    if (cntb <= C8_CAP) {
        for (int s = t; s < cntb; s += 256) {
            int2 pay = tmp[r0 + s];
            int l = (pay.x >> auxShift) & lowmask;
            int pos = atomicAdd(&curl[l], 1);
            stage[pos] = pay;
        }
        __syncthreads();
        for (int s = t; s < cntb; s += 256) dst[r0 + s] = stage[s];
    } else {
        for (int s = t; s < cntb; s += 256) {
            int2 pay = tmp[r0 + s];
            int l = (pay.x >> auxShift) & lowmask;
            int pos = atomicAdd(&curl[l], 1);
            dst[r0 + pos] = pay;
        }
    }
}

__global__ __launch_bounds__(256) void k_binC_all(const unsigned* __restrict__ kg_tmp,
        const int* __restrict__ kg_boff, unsigned* __restrict__ kg_tr, int* __restrict__ kg_off,
        const int2* __restrict__ ui_tmp, const int* __restrict__ ui_boff,
        int2* __restrict__ ui_iw, int* __restrict__ ui_off,
        const int2* __restrict__ iu_tmp, const int* __restrict__ iu_boff,
        int2* __restrict__ iu_iw, int* __restrict__ iu_off) {
    __shared__ SmC sm;
    __shared__ int curl[512];
    __shared__ int sc[256];
    int bid = blockIdx.x;
    int t = threadIdx.x;
    if (bid < NB_CKG) {
        int b = bid;
        int nbase = b << 9;
        int nlim = NE - nbase; if (nlim > 512) nlim = 512;
        if (nlim <= 0) return;
        int r0 = kg_boff[b];
        int r1 = kg_boff[b + 1];
        int cntb = r1 - r0;
        curl[t] = 0; curl[t + 256] = 0;
        __syncthreads();
        for (int s = t; s < cntb; s += 256)
            atomicAdd(&curl[(kg_tmp[r0 + s] >> 21) & 511], 1);
        __syncthreads();
        int v0 = curl[2 * t], v1 = curl[2 * t + 1];
        int s2 = v0 + v1;
        sc[t] = s2;
        __syncthreads();
        for (int o = 1; o < 256; o <<= 1) {
            int u = (t >= o) ? sc[t - o] : 0;
            __syncthreads();
            sc[t] += u;
            __syncthreads();
        }
        int excl = sc[t] - s2;
        curl[2 * t] = excl;
        curl[2 * t + 1] = excl + v0;
        if (2 * t < nlim) kg_off[nbase + 2 * t] = r0 + excl;
        if (2 * t + 1 < nlim) kg_off[nbase + 2 * t + 1] = r0 + excl + v0;
        if (b == NB_CKG - 1 && t == 0) kg_off[nbase + nlim] = r1;   // sentinel off[NE]
        __syncthreads();
        if (cntb <= KG_CAP) {
            for (int s = t; s < cntb; s += 256) {
                unsigned pay = kg_tmp[r0 + s];
                int l = (pay >> 21) & 511;
                int pos = atomicAdd(&curl[l], 1);
                sm.u.kgstage[pos] = pay;
            }
            __syncthreads();
            for (int s = t; s < cntb; s += 256) kg_tr[r0 + s] = sm.u.kgstage[s];
        } else {
            for (int s = t; s < cntb; s += 256) {
                unsigned pay = kg_tmp[r0 + s];
                int l = (pay >> 21) & 511;
                int pos = atomicAdd(&curl[l], 1);
                kg_tr[r0 + pos] = pay;
            }
        }
    } else if (bid < NB_CKG + NB_CUI) {
        binC8_body(ui_tmp, ui_boff, ui_iw, ui_off, NU, 8, 17,
                   bid - NB_CKG, NB_CUI, sm.u.c8stage, curl, sc);
    } else {
        binC8_body(iu_tmp, iu_boff, iu_iw, iu_off, NE, 9, 16,
                   bid - NB_CKG - NB_CUI, NB_CIU, sm.u.c8stage, curl, sc);
    }
}

// ---- fused per-layer kernel (R6 separate-table layout; inner math bit-identical).
// FIRST=true: eacc/uacc stores (buffers start undefined; no memset needed).
// FINAL=true: folds k_final epilogue, skips fp16/acc write-backs.
// Payload streams (kg_tr, iu_iw, ui_iw) use nontemporal loads: single-use data,
// keeps L2 free for the hot qm/ent/usr gather tables.
template<bool FIRST, bool FINAL>
__global__ __launch_bounds__(256) void k_layer(const __half* __restrict__ qmH,
        const __half* __restrict__ relH, const __half* __restrict__ entH,
        const __half* __restrict__ usrH,
        const int* __restrict__ kg_off, const unsigned* __restrict__ kg_tr,
        const int* __restrict__ iu_off, const int2* __restrict__ iu_iw,
        const int* __restrict__ ui_off, const int2* __restrict__ ui_iw,
        float* __restrict__ eacc, __half* __restrict__ entHout,
        float* __restrict__ uacc, __half* __restrict__ usrHout,
        const float* __restrict__ ent0, const float* __restrict__ usr0,
        float* __restrict__ out) {
    int w = __builtin_amdgcn_readfirstlane(threadIdx.x >> 6);
    int lane = threadIdx.x & 63;
    int sub = lane >> 3;          // edge slot 0..7
    int li  = lane & 7;           // dims 8li..8li+7
    const float SC = 0.17677669529663687f; // 1/sqrt(32)
    const float NEG = -1e30f;
    const float inv3 = 1.f / 3.f;
    const int4* qmI  = (const int4*)qmH;
    const int4* entI = (const int4*)entH;
    const int4* relI = (const int4*)relH;
    const int4* usrI = (const int4*)usrH;

    if (blockIdx.x < NEB) {
        // ================= entity path =================
        int node = blockIdx.x * 4 + w;
        U16 qh; qh.v = qmI[(long)node * 8 + li];
        int b0 = kg_off[node], b1 = kg_off[node + 1];
        int deg = b1 - b0;

        float ssum = 0.f;
        float acc[8] = {0.f, 0.f, 0.f, 0.f, 0.f, 0.f, 0.f, 0.f};
        if (deg > 0) {
            int s = b0;
            int i0 = s + sub;
            unsigned tr = ntld_u(&kg_tr[i0 < b1 ? i0 : b1 - 1]);
            for (; s < b1; s += 8) {
                int ni = s + 8 + sub;
                unsigned trn = ntld_u(&kg_tr[ni < b1 ? ni : b1 - 1]);  // prefetch next payload
                bool has = (s + sub) < b1;
                int tl = tr & 0x1FFFF, rr = (tr >> 17) & 15;
                U16 rl; rl.v = relI[rr * 8 + li];
                U16 qt; qt.v = qmI[(long)tl * 8 + li];
                U16 ev; ev.v = entI[(long)tl * 8 + li];
                float p = 0.f;
#pragma unroll
                for (int k = 0; k < 4; k++) {
                    __half2 kk = __hmul2(qt.h[k], rl.h[k]);
                    p = fdot2a(qh.h[k], kk, p);
                }
                p = dpp_red4(p);
                float e = __expf(has ? p * SC : NEG);
                ssum += e;
#pragma unroll
                for (int k = 0; k < 4; k++) {
                    __half2 v2 = __hmul2(ev.h[k], rl.h[k]);
                    float2 vf = __half22float2(v2);
                    acc[2 * k]     += vf.x * e;
                    acc[2 * k + 1] += vf.y * e;
                }
                tr = trn;
            }
#pragma unroll
            for (int o = 8; o <= 32; o <<= 1) {
                ssum += __shfl_xor(ssum, o, 64);
#pragma unroll
                for (int k = 0; k < 8; k++) acc[k] += __shfl_xor(acc[k], o, 64);
            }
            float inv = 1.f / ssum;
#pragma unroll
            for (int k = 0; k < 8; k++) acc[k] *= inv;
            float ss = 0.f;
#pragma unroll
            for (int k = 0; k < 8; k++) ss += acc[k] * acc[k];
            ss += __shfl_xor(ss, 1, 64);
            ss += __shfl_xor(ss, 2, 64);
            ss += __shfl_xor(ss, 4, 64);
            float nsc = 1.f / fmaxf(sqrtf(ss), 1e-12f);
#pragma unroll
            for (int k = 0; k < 8; k++) acc[k] *= nsc;
        }

        // user -> entity gather
        int c0 = iu_off[node], c1 = iu_off[node + 1];
        if (c1 > c0) {
            float ua[8] = {0.f, 0.f, 0.f, 0.f, 0.f, 0.f, 0.f, 0.f};
            int t2 = c0;
            int j0 = t2 + sub;
            int2 pw = ntld_i2(&iu_iw[j0 < c1 ? j0 : c1 - 1]);
            for (; t2 < c1; t2 += 8) {
                int nj = t2 + 8 + sub;
                int2 pwn = ntld_i2(&iu_iw[nj < c1 ? nj : c1 - 1]);
                bool has = (t2 + sub) < c1;
                float wv = has ? __int_as_float(pw.y) : 0.f;
                U16 uu; uu.v = usrI[(long)(pw.x & 0xFFFF) * 8 + li];
#pragma unroll
                for (int k = 0; k < 4; k++) {
                    float2 uf = __half22float2(uu.h[k]);
                    ua[2 * k]     += wv * uf.x;
                    ua[2 * k + 1] += wv * uf.y;
                }
                pw = pwn;
            }
#pragma unroll
            for (int o = 8; o <= 32; o <<= 1) {
#pragma unroll
                for (int k = 0; k < 8; k++) ua[k] += __shfl_xor(ua[k], o, 64);
            }
#pragma unroll
            for (int k = 0; k < 8; k++) acc[k] += ua[k];
        }

        if (sub == 0) {
            long base = (long)node * 16 + 2 * li;
            float4* eacc4 = (float4*)eacc;
            float4 e0, e1;
            if (FIRST) {
                e0.x = acc[0]; e0.y = acc[1]; e0.z = acc[2]; e0.w = acc[3];
                e1.x = acc[4]; e1.y = acc[5]; e1.z = acc[6]; e1.w = acc[7];
            } else {
                e0 = eacc4[base]; e1 = eacc4[base + 1];
                e0.x += acc[0]; e0.y += acc[1]; e0.z += acc[2]; e0.w += acc[3];
                e1.x += acc[4]; e1.y += acc[5]; e1.z += acc[6]; e1.w += acc[7];
            }
            if (!FINAL) {
                eacc4[base] = e0; eacc4[base + 1] = e1;
                U16 ho;
                ho.h[0] = __floats2half2_rn(acc[0], acc[1]);
                ho.h[1] = __floats2half2_rn(acc[2], acc[3]);
                ho.h[2] = __floats2half2_rn(acc[4], acc[5]);
                ho.h[3] = __floats2half2_rn(acc[6], acc[7]);
                ((int4*)entHout)[(long)node * 8 + li] = ho.v;
            } else {
                const float4* a4 = (const float4*)ent0;
                float4 a0 = a4[base], a1 = a4[base + 1];
                float4 o0, o1;
                o0.x = (a0.x + e0.x) * inv3; o0.y = (a0.y + e0.y) * inv3;
                o0.z = (a0.z + e0.z) * inv3; o0.w = (a0.w + e0.w) * inv3;
                o1.x = (a1.x + e1.x) * inv3; o1.y = (a1.y + e1.y) * inv3;
                o1.z = (a1.z + e1.z) * inv3; o1.w = (a1.w + e1.w) * inv3;
                float4* oute = (float4*)out + (long)NU * 16;
                oute[base] = o0; oute[base + 1] = o1;
            }
        }
    } else {
        // ================= user path =================
        int node = (blockIdx.x - NEB) * 4 + w;
        int b0 = ui_off[node], b1 = ui_off[node + 1];
        float ax[8] = {0.f, 0.f, 0.f, 0.f, 0.f, 0.f, 0.f, 0.f};
        if (b1 > b0) {
            int s = b0;
            int j0 = s + sub;
            int2 pw = ntld_i2(&ui_iw[j0 < b1 ? j0 : b1 - 1]);
            for (; s < b1; s += 8) {
                int nj = s + 8 + sub;
                int2 pwn = ntld_i2(&ui_iw[nj < b1 ? nj : b1 - 1]);
                bool has = (s + sub) < b1;
                float wv = has ? __int_as_float(pw.y) : 0.f;
                U16 uu; uu.v = entI[(long)(pw.x & 0x1FFFF) * 8 + li];
#pragma unroll
                for (int k = 0; k < 4; k++) {
                    float2 uf = __half22float2(uu.h[k]);
                    ax[2 * k]     += wv * uf.x;
                    ax[2 * k + 1] += wv * uf.y;
                }
                pw = pwn;
            }
#pragma unroll
            for (int o = 8; o <= 32; o <<= 1) {
#pragma unroll
                for (int k = 0; k < 8; k++) ax[k] += __shfl_xor(ax[k], o, 64);
            }
        }
        if (sub == 0) {
            long base = (long)node * 16 + 2 * li;
            float4* uacc4 = (float4*)uacc;
            float4 u0, u1;
            if (FIRST) {
                u0.x = ax[0]; u0.y = ax[1]; u0.z = ax[2]; u0.w = ax[3];
                u1.x = ax[4]; u1.y = ax[5]; u1.z = ax[6]; u1.w = ax[7];
            } else {
                u0 = uacc4[base]; u1 = uacc4[base + 1];
                u0.x += ax[0]; u0.y += ax[1]; u0.z += ax[2]; u0.w += ax[3];
                u1.x += ax[4]; u1.y += ax[5]; u1.z += ax[6]; u1.w += ax[7];
            }
            if (!FINAL) {
                uacc4[base] = u0; uacc4[base + 1] = u1;
                U16 ho;
                ho.h[0] = __floats2half2_rn(ax[0], ax[1]);
                ho.h[1] = __floats2half2_rn(ax[2], ax[3]);
                ho.h[2] = __floats2half2_rn(ax[4], ax[5]);
                ho.h[3] = __floats2half2_rn(ax[6], ax[7]);
                ((int4*)usrHout)[(long)node * 8 + li] = ho.v;
            } else {
                const float4* a4 = (const float4*)usr0;
                float4 a0 = a4[base], a1 = a4[base + 1];
                float4 o0, o1;
                o0.x = (a0.x + u0.x) * inv3; o0.y = (a0.y + u0.y) * inv3;
                o0.z = (a0.z + u0.z) * inv3; o0.w = (a0.w + u0.w) * inv3;
                o1.x = (a1.x + u1.x) * inv3; o1.y = (a1.y + u1.y) * inv3;
                o1.z = (a1.z + u1.z) * inv3; o1.w = (a1.w + u1.w) * inv3;
                float4* outu = (float4*)out;
                outu[base] = o0; outu[base + 1] = o1;
            }
        }
    }
}

extern "C" void kernel_launch(void* const* d_in, const int* in_sizes, int n_in,
                              void* d_out, int out_size, void* d_ws, size_t ws_size,
                              hipStream_t stream) {
    const float* usr0  = (const float*)d_in[1];
    const float* ent0  = (const float*)d_in[2];
    const int*   inter = (const int*)d_in[3];
    const float* iwf   = (const float*)d_in[4];
    const int*   eidx  = (const int*)d_in[5];
    const int*   etype = (const int*)d_in[6];
    const float* relf  = (const float*)d_in[7];
    const float* wqf   = (const float*)d_in[8];
    float* out = (float*)d_out;

    const int* eh = eidx;
    const int* et = eidx + EKG;
    const int* iu = inter;
    const int* ii = inter + EIN;

    // ---- workspace layout (4B words) ----
    float* p = (float*)d_ws;
    float* eacc = p;  p += (long)NE * DIM;
    float* uacc = p;  p += (long)NU * DIM;
    __half* qmH   = (__half*)p;  p += (long)NE * DIM / 2;
    __half* entHa = (__half*)p;  p += (long)NE * DIM / 2;
    __half* entHb = (__half*)p;  p += (long)NE * DIM / 2;
    __half* usrHa = (__half*)p;  p += (long)NU * DIM / 2;
    __half* usrHb = (__half*)p;  p += (long)NU * DIM / 2;
    __half* relH  = (__half*)p;  p += (long)NRELS * DIM / 2;
    int* cntK = (int*)p;        p += 256;
    int* cntU = (int*)p;        p += 256;
    int* cntI = (int*)p;        p += 256;
    int* kg_boff = (int*)p;     p += 256;
    int* ui_boff = (int*)p;     p += 256;
    int* iu_boff = (int*)p;     p += 256;
    int* kg_off = (int*)p;      p += NE + 2;
    int* ui_off = (int*)p;      p += NU + 2;
    int* iu_off = (int*)p;      p += NE + 2;
    int* kg_g   = (int*)p;      p += 256;
    int* ui_g   = (int*)p;      p += 256;
    int* iu_g   = (int*)p;      p += 256;
    unsigned* kg_tr  = (unsigned*)p; p += EKG;
    unsigned* kg_tmp = (unsigned*)p; p += EKG;
    int2* ui_iw  = (int2*)p;    p += (long)EIN * 2;
    int2* ui_tmp = (int2*)p;    p += (long)EIN * 2;
    int2* iu_iw  = (int2*)p;    p += (long)EIN * 2;
    int2* iu_tmp = (int2*)p;    p += (long)EIN * 2;

    const int B = 256;

    // ---- init: bucket counters only (eacc/uacc written in store-mode) ----
    hipMemsetAsync(cntK, 0, (size_t)768 * 4, stream);
    k_castH<<<(NU * 16 + B - 1) / B, B, 0, stream>>>((const float4*)usr0, (const float4*)relf,
                                                     (int2*)usrHa, (int2*)relH);

    // ---- CSR build ----
    k_hist_bucket<<<512, 256, 0, stream>>>(eh, iu, ii, cntK, cntU, cntI);
    k_bucket_scan<<<1, 256, 0, stream>>>(cntK, cntU, cntI, kg_boff, ui_boff, iu_boff,
                                         kg_g, ui_g, iu_g);
    k_binB_all<<<NB_BKG + NB_B8 + NB_B8, 256, 0, stream>>>(eh, et, etype, kg_g, kg_tmp,
                                                           iu, ii, iwf,
                                                           ui_g, ui_tmp, iu_g, iu_tmp);
    k_binC_all<<<NB_CKG + NB_CUI + NB_CIU, 256, 0, stream>>>(kg_tmp, kg_boff, kg_tr, kg_off,
                                                             ui_tmp, ui_boff, ui_iw, ui_off,
                                                             iu_tmp, iu_boff, iu_iw, iu_off);

    // ---- layer 0 ----
    k_gemm_f<<<NE / 16, 256, 0, stream>>>(ent0, wqf, qmH, entHa);
    k_layer<true, false><<<NEB + NUB, 256, 0, stream>>>(qmH, relH, entHa, usrHa,
                                                        kg_off, kg_tr, iu_off, iu_iw,
                                                        ui_off, ui_iw,
                                                        eacc, entHb, uacc, usrHb,
                                                        nullptr, nullptr, nullptr);
    // ---- layer 1 (folds k_final) ----
    k_gemm_h<<<NE / 16, 256, 0, stream>>>(entHb, wqf, qmH);
    k_layer<false, true><<<NEB + NUB, 256, 0, stream>>>(qmH, relH, entHb, usrHb,
                                                        kg_off, kg_tr, iu_off, iu_iw,
                                                        ui_off, ui_iw,
                                                        eacc, nullptr, uacc, nullptr,
                                                        ent0, usr0, out);
}

// Round 9
// 474.281 us; speedup vs baseline: 1.0696x; 1.0502x over previous
//
#include <hip/hip_runtime.h>
#include <hip/hip_fp16.h>

#define NU 50000
#define NE 100000
#define DIM 64
#define NRELS 16
#define EKG 1500000
#define EIN 1000000

#define KG_CHUNK 8192
#define KG_NBUCK ((NE + 511) >> 9)   // 196
#define B8_CHUNK 4096
#define KG_CAP 9216                  // Binomial mean 7680, sigma 87 -> +17s
#define C8_CAP 6656                  // mean 5120, sigma 71 -> +21s

#define NEB (NE / 4)                 // 25000 ent blocks
#define NUB (NU / 4)                 // 12500 usr blocks

#define NB_BKG ((EKG + KG_CHUNK - 1) / KG_CHUNK)   // 184
#define NB_B8  ((EIN + B8_CHUNK - 1) / B8_CHUNK)   // 245
#define NB_CKG KG_NBUCK                             // 196
#define NB_CUI ((NU + 255) >> 8)                    // 196
#define NB_CIU ((NE + 511) >> 9)                    // 196

typedef _Float16 f16x2 __attribute__((ext_vector_type(2)));

union U16 { int4 v; __half2 h[4]; };
union H4 { int2 i2; __half2 h[2]; };

__device__ __forceinline__ float fdot2a(__half2 a, __half2 b, float c) {
#if __has_builtin(__builtin_amdgcn_fdot2)
    union { __half2 h; f16x2 v; } ua, ub;
    ua.h = a; ub.h = b;
    return __builtin_amdgcn_fdot2(ua.v, ub.v, c, false);
#else
    return c + __half2float(a.x) * __half2float(b.x) + __half2float(a.y) * __half2float(b.y);
#endif
}

// sum over each 4-lane quad via DPP (score reduce; head = quad)
__device__ __forceinline__ float dpp_red4(float p) {
    int t;
    t = __builtin_amdgcn_update_dpp(0, __float_as_int(p), 0xB1, 0xF, 0xF, true);  // quad_perm xor1
    p += __int_as_float(t);
    t = __builtin_amdgcn_update_dpp(0, __float_as_int(p), 0x4E, 0xF, 0xF, true);  // quad_perm xor2
    p += __int_as_float(t);
    return p;
}

// fp16 mirror cast for usr + rel (ent cast folded into k_gemm_f)
__global__ void k_castH(const float4* __restrict__ u4, const float4* __restrict__ r4,
                        int2* __restrict__ uH, int2* __restrict__ rH) {
    int i = blockIdx.x * blockDim.x + threadIdx.x;
    if (i < NU * 16) {
        float4 v = u4[i];
        H4 o; o.h[0] = __floats2half2_rn(v.x, v.y); o.h[1] = __floats2half2_rn(v.z, v.w);
        uH[i] = o.i2;
    }
    if (i < NRELS * 16) {
        float4 v = r4[i];
        H4 o; o.h[0] = __floats2half2_rn(v.x, v.y); o.h[1] = __floats2half2_rn(v.z, v.w);
        rH[i] = o.i2;
    }
}

// qm = ent0 @ WQ -> fp16; ALSO casts ent0 -> entH (rows already staged in LDS).
__global__ __launch_bounds__(256) void k_gemm_f(const float* __restrict__ ent,
                                                const float* __restrict__ wq,
                                                __half* __restrict__ qmH,
                                                __half* __restrict__ entH) {
    __shared__ float sW[64 * 64];
    __shared__ float sR[16 * 64];
    int t = threadIdx.x;
    for (int i = t; i < 4096; i += 256) sW[i] = wq[i];
    long row0 = (long)blockIdx.x * 16;
    for (int i = t; i < 1024; i += 256) sR[i] = ent[row0 * 64 + i];
    __syncthreads();
    int r = t >> 4, cg = t & 15;
    const float4* sW4 = (const float4*)sW;
    const float4* sR4 = (const float4*)sR;
    float4 acc = {0.f, 0.f, 0.f, 0.f};
#pragma unroll
    for (int k = 0; k < 64; k++) {
        float a = sR[r * 64 + k];
        float4 wv = sW4[k * 16 + cg];
        acc.x += a * wv.x; acc.y += a * wv.y; acc.z += a * wv.z; acc.w += a * wv.w;
    }
    H4 o;
    o.h[0] = __floats2half2_rn(acc.x, acc.y);
    o.h[1] = __floats2half2_rn(acc.z, acc.w);
    ((int2*)qmH)[(row0 + r) * 16 + cg] = o.i2;
    float4 ev = sR4[r * 16 + cg];
    H4 e;
    e.h[0] = __floats2half2_rn(ev.x, ev.y);
    e.h[1] = __floats2half2_rn(ev.z, ev.w);
    ((int2*)entH)[(row0 + r) * 16 + cg] = e.i2;
}

// layer-1 gemm: fp16 ent input
__global__ __launch_bounds__(256) void k_gemm_h(const __half* __restrict__ ent,
                                                const float* __restrict__ wq,
                                                __half* __restrict__ qmH) {
    __shared__ float sW[64 * 64];
    __shared__ float sR[16 * 64];
    int t = threadIdx.x;
    for (int i = t; i < 4096; i += 256) sW[i] = wq[i];
    long row0 = (long)blockIdx.x * 16;
    const __half2* e2 = (const __half2*)ent;
    for (int i = t; i < 512; i += 256) {
        float2 f = __half22float2(e2[row0 * 32 + i]);
        sR[2 * i] = f.x; sR[2 * i + 1] = f.y;
    }
    __syncthreads();
    int r = t >> 4, cg = t & 15;
    const float4* sW4 = (const float4*)sW;
    float4 acc = {0.f, 0.f, 0.f, 0.f};
#pragma unroll
    for (int k = 0; k < 64; k++) {
        float a = sR[r * 64 + k];
        float4 wv = sW4[k * 16 + cg];
        acc.x += a * wv.x; acc.y += a * wv.y; acc.z += a * wv.z; acc.w += a * wv.w;
    }
    H4 o;
    o.h[0] = __floats2half2_rn(acc.x, acc.y);
    o.h[1] = __floats2half2_rn(acc.z, acc.w);
    ((int2*)qmH)[(row0 + r) * 16 + cg] = o.i2;
}

// ---- bucket-level histogram (LDS-privatized) ----
__global__ __launch_bounds__(256) void k_hist_bucket(const int* __restrict__ eh,
        const int* __restrict__ iu, const int* __restrict__ ii,
        int* __restrict__ cntK, int* __restrict__ cntU, int* __restrict__ cntI) {
    __shared__ int sK[256], sU[256], sI[256];
    int t = threadIdx.x;
    sK[t] = 0; sU[t] = 0; sI[t] = 0;
    __syncthreads();
    int stride = gridDim.x * 256;
    for (int e = blockIdx.x * 256 + t; e < EKG; e += stride)
        atomicAdd(&sK[eh[e] >> 9], 1);
    for (int e = blockIdx.x * 256 + t; e < EIN; e += stride) {
        atomicAdd(&sU[iu[e] >> 8], 1);
        atomicAdd(&sI[ii[e] >> 9], 1);
    }
    __syncthreads();
    if (sK[t]) atomicAdd(&cntK[t], sK[t]);
    if (sU[t]) atomicAdd(&cntU[t], sU[t]);
    if (sI[t]) atomicAdd(&cntI[t], sI[t]);
}

// ---- tiny scans: bucket counts -> bucket offsets + gcur init ----
__global__ __launch_bounds__(256) void k_bucket_scan(const int* __restrict__ cntK,
        const int* __restrict__ cntU, const int* __restrict__ cntI,
        int* __restrict__ kg_boff, int* __restrict__ ui_boff, int* __restrict__ iu_boff,
        int* __restrict__ kg_g, int* __restrict__ ui_g, int* __restrict__ iu_g) {
    __shared__ int sc[256];
    int t = threadIdx.x;
#define SCAN1(cnt, boff, gcur) { \
    int v = cnt[t]; sc[t] = v; __syncthreads(); \
    for (int o = 1; o < 256; o <<= 1) { \
        int u = (t >= o) ? sc[t - o] : 0; __syncthreads(); sc[t] += u; __syncthreads(); } \
    int e = sc[t] - v; boff[t] = e; gcur[t] = e; \
    __syncthreads(); }
    SCAN1(cntK, kg_boff, kg_g)
    SCAN1(cntU, ui_boff, ui_g)
    SCAN1(cntI, iu_boff, iu_g)
#undef SCAN1
}

// ---- merged pass B ----
struct SmB {
    union {
        struct { unsigned stage[KG_CHUNK]; int dest[KG_CHUNK]; } kg;
        struct { int2 stage[B8_CHUNK]; int dest[B8_CHUNK]; } b8;
    } u;
};

__device__ __forceinline__ void binB8_body(const int* __restrict__ key,
        const int* __restrict__ aux, const float* __restrict__ wv, int nE,
        int shift, int auxShift, int* __restrict__ gcur, int2* __restrict__ tmp,
        int cb, int2* stage, int* dest,
        int* cnt, int* boff, int* gbase, int* curl, int* sc) {
    int t = threadIdx.x;
    int base = cb * B8_CHUNK;
    int nloc = nE - base; if (nloc > B8_CHUNK) nloc = B8_CHUNK;
    cnt[t] = 0;
    __syncthreads();
    for (int i = t; i < nloc; i += 256)
        atomicAdd(&cnt[key[base + i] >> shift], 1);
    __syncthreads();
    int v = cnt[t];
    sc[t] = v;
    __syncthreads();
    for (int o = 1; o < 256; o <<= 1) {
        int u = (t >= o) ? sc[t - o] : 0;
        __syncthreads();
        sc[t] += u;
        __syncthreads();
    }
    boff[t] = sc[t] - v;
    curl[t] = sc[t] - v;
    gbase[t] = atomicAdd(&gcur[t], v);
    __syncthreads();
    int lowmask = (1 << shift) - 1;
    for (int i = t; i < nloc; i += 256) {
        int e = base + i;
        int k = key[e];
        int b = k >> shift;
        int2 pay;
        pay.x = aux[e] | ((k & lowmask) << auxShift);
        pay.y = __float_as_int(wv[e]);
        int pos = atomicAdd(&curl[b], 1);
        stage[pos] = pay;
        dest[pos] = gbase[b] + (pos - boff[b]);
    }
    __syncthreads();
    for (int s = t; s < nloc; s += 256) tmp[dest[s]] = stage[s];
}

__global__ __launch_bounds__(256) void k_binB_all(const int* __restrict__ eh,
        const int* __restrict__ et, const int* __restrict__ ety,
        int* __restrict__ kg_g, unsigned* __restrict__ kg_tmp,
        const int* __restrict__ iu, const int* __restrict__ ii,
        const float* __restrict__ iwf,
        int* __restrict__ ui_g, int2* __restrict__ ui_tmp,
        int* __restrict__ iu_g, int2* __restrict__ iu_tmp) {
    __shared__ SmB sm;
    __shared__ int cnt[256], boff[256], gbase[256], curl[256], sc[256];
    int bid = blockIdx.x;
    int t = threadIdx.x;
    if (bid < NB_BKG) {
        int base = bid * KG_CHUNK;
        int nloc = EKG - base; if (nloc > KG_CHUNK) nloc = KG_CHUNK;
        for (int i = t; i < KG_NBUCK; i += 256) cnt[i] = 0;
        __syncthreads();
        for (int i = t; i < nloc; i += 256)
            atomicAdd(&cnt[eh[base + i] >> 9], 1);
        __syncthreads();
        int v = (t < KG_NBUCK) ? cnt[t] : 0;
        sc[t] = v;
        __syncthreads();
        for (int o = 1; o < 256; o <<= 1) {
            int u = (t >= o) ? sc[t - o] : 0;
            __syncthreads();
            sc[t] += u;
            __syncthreads();
        }
        if (t < KG_NBUCK) {
            boff[t] = sc[t] - v;
            curl[t] = sc[t] - v;
            gbase[t] = atomicAdd(&kg_g[t], v);
        }
        __syncthreads();
        for (int i = t; i < nloc; i += 256) {
            int e = base + i;
            int h = eh[e];
            int b = h >> 9;
            unsigned pay = (unsigned)et[e] | ((unsigned)(ety[e] - 1) << 17)
                         | ((unsigned)(h & 511) << 21);
            int pos = atomicAdd(&curl[b], 1);
            sm.u.kg.stage[pos] = pay;
            sm.u.kg.dest[pos] = gbase[b] + (pos - boff[b]);
        }
        __syncthreads();
        for (int s = t; s < nloc; s += 256) kg_tmp[sm.u.kg.dest[s]] = sm.u.kg.stage[s];
    } else if (bid < NB_BKG + NB_B8) {
        binB8_body(iu, ii, iwf, EIN, 8, 17, ui_g, ui_tmp, bid - NB_BKG,
                   sm.u.b8.stage, sm.u.b8.dest, cnt, boff, gbase, curl, sc);
    } else {
        binB8_body(ii, iu, iwf, EIN, 9, 16, iu_g, iu_tmp, bid - NB_BKG - NB_B8,
                   sm.u.b8.stage, sm.u.b8.dest, cnt, boff, gbase, curl, sc);
    }
}

// ---- merged pass C ----
struct SmC {
    union {
        unsigned kgstage[KG_CAP];
        int2 c8stage[C8_CAP];
    } u;
};

__device__ __forceinline__ void binC8_body(const int2* __restrict__ tmp,
        const int* __restrict__ boffg, int2* __restrict__ dst, int* __restrict__ off,
        int nnodes, int shift, int auxShift, int lb, int nb,
        int2* stage, int* curl, int* sc) {
    int b = lb;
    int nbase = b << shift;
    int nlim = nnodes - nbase; if (nlim > (1 << shift)) nlim = 1 << shift;
    if (nlim <= 0) return;
    int t = threadIdx.x;
    int r0 = boffg[b];
    int r1 = boffg[b + 1];
    int cntb = r1 - r0;
    int lowmask = (1 << shift) - 1;
    curl[t] = 0; curl[t + 256] = 0;
    __syncthreads();
    for (int s = t; s < cntb; s += 256)
        atomicAdd(&curl[(tmp[r0 + s].x >> auxShift) & lowmask], 1);
    __syncthreads();
    int v0 = curl[2 * t], v1 = curl[2 * t + 1];
    int s2 = v0 + v1;
    sc[t] = s2;
    __syncthreads();
    for (int o = 1; o < 256; o <<= 1) {
        int u = (t >= o) ? sc[t - o] : 0;
        __syncthreads();
        sc[t] += u;
        __syncthreads();
    }
    int excl = sc[t] - s2;
    curl[2 * t] = excl;
    curl[2 * t + 1] = excl + v0;
    if (2 * t < nlim) off[nbase + 2 * t] = r0 + excl;
    if (2 * t + 1 < nlim) off[nbase + 2 * t + 1] = r0 + excl + v0;
    if (b == nb - 1 && t == 0) off[nbase + nlim] = r1;  // sentinel
    __syncthreads();
    if (cntb <= C8_CAP) {
        for (int s = t; s < cntb; s += 256) {
            int2 pay = tmp[r0 + s];
            int l = (pay.x >> auxShift) & lowmask;
            int pos = atomicAdd(&curl[l], 1);
            stage[pos] = pay;
        }
        __syncthreads();
        for (int s = t; s < cntb; s += 256) dst[r0 + s] = stage[s];
    } else {
        for (int s = t; s < cntb; s += 256) {
            int2 pay = tmp[r0 + s];
            int l = (pay.x >> auxShift) & lowmask;
            int pos = atomicAdd(&curl[l], 1);
            dst[r0 + pos] = pay;
        }
    }
}

__global__ __launch_bounds__(256) void k_binC_all(const unsigned* __restrict__ kg_tmp,
        const int* __restrict__ kg_boff, unsigned* __restrict__ kg_tr, int* __restrict__ kg_off,
        const int2* __restrict__ ui_tmp, const int* __restrict__ ui_boff,
        int2* __restrict__ ui_iw, int* __restrict__ ui_off,
        const int2* __restrict__ iu_tmp, const int* __restrict__ iu_boff,
        int2* __restrict__ iu_iw, int* __restrict__ iu_off) {
    __shared__ SmC sm;
    __shared__ int curl[512];
    __shared__ int sc[256];
    int bid = blockIdx.x;
    int t = threadIdx.x;
    if (bid < NB_CKG) {
        int b = bid;
        int nbase = b << 9;
        int nlim = NE - nbase; if (nlim > 512) nlim = 512;
        if (nlim <= 0) return;
        int r0 = kg_boff[b];
        int r1 = kg_boff[b + 1];
        int cntb = r1 - r0;
        curl[t] = 0; curl[t + 256] = 0;
        __syncthreads();
        for (int s = t; s < cntb; s += 256)
            atomicAdd(&curl[(kg_tmp[r0 + s] >> 21) & 511], 1);
        __syncthreads();
        int v0 = curl[2 * t], v1 = curl[2 * t + 1];
        int s2 = v0 + v1;
        sc[t] = s2;
        __syncthreads();
        for (int o = 1; o < 256; o <<= 1) {
            int u = (t >= o) ? sc[t - o] : 0;
            __syncthreads();
            sc[t] += u;
            __syncthreads();
        }
        int excl = sc[t] - s2;
        curl[2 * t] = excl;
        curl[2 * t + 1] = excl + v0;
        if (2 * t < nlim) kg_off[nbase + 2 * t] = r0 + excl;
        if (2 * t + 1 < nlim) kg_off[nbase + 2 * t + 1] = r0 + excl + v0;
        if (b == NB_CKG - 1 && t == 0) kg_off[nbase + nlim] = r1;   // sentinel off[NE]
        __syncthreads();
        if (cntb <= KG_CAP) {
            for (int s = t; s < cntb; s += 256) {
                unsigned pay = kg_tmp[r0 + s];
                int l = (pay >> 21) & 511;
                int pos = atomicAdd(&curl[l], 1);
                sm.u.kgstage[pos] = pay;
            }
            __syncthreads();
            for (int s = t; s < cntb; s += 256) kg_tr[r0 + s] = sm.u.kgstage[s];
        } else {
            for (int s = t; s < cntb; s += 256) {
                unsigned pay = kg_tmp[r0 + s];
                int l = (pay >> 21) & 511;
                int pos = atomicAdd(&curl[l], 1);
                kg_tr[r0 + pos] = pay;
            }
        }
    } else if (bid < NB_CKG + NB_CUI) {
        binC8_body(ui_tmp, ui_boff, ui_iw, ui_off, NU, 8, 17,
                   bid - NB_CKG, NB_CUI, sm.u.c8stage, curl, sc);
    } else {
        binC8_body(iu_tmp, iu_boff, iu_iw, iu_off, NE, 9, 16,
                   bid - NB_CKG - NB_CUI, NB_CIU, sm.u.c8stage, curl, sc);
    }
}

// ---- fused per-layer kernel (R6 separate-table layout; inner math bit-identical;
// plain cached loads for payloads — NT loads regressed in R8: payload lines are
// shared across ~8 waves, L2 must serve the re-reads).
// FIRST=true: eacc/uacc stores (buffers start undefined; no memset needed).
// FINAL=true: folds k_final epilogue, skips fp16/acc write-backs.
template<bool FIRST, bool FINAL>
__global__ __launch_bounds__(256) void k_layer(const __half* __restrict__ qmH,
        const __half* __restrict__ relH, const __half* __restrict__ entH,
        const __half* __restrict__ usrH,
        const int* __restrict__ kg_off, const unsigned* __restrict__ kg_tr,
        const int* __restrict__ iu_off, const int2* __restrict__ iu_iw,
        const int* __restrict__ ui_off, const int2* __restrict__ ui_iw,
        float* __restrict__ eacc, __half* __restrict__ entHout,
        float* __restrict__ uacc, __half* __restrict__ usrHout,
        const float* __restrict__ ent0, const float* __restrict__ usr0,
        float* __restrict__ out) {
    int w = __builtin_amdgcn_readfirstlane(threadIdx.x >> 6);
    int lane = threadIdx.x & 63;
    int sub = lane >> 3;          // edge slot 0..7
    int li  = lane & 7;           // dims 8li..8li+7
    const float SC = 0.17677669529663687f; // 1/sqrt(32)
    const float NEG = -1e30f;
    const float inv3 = 1.f / 3.f;
    const int4* qmI  = (const int4*)qmH;
    const int4* entI = (const int4*)entH;
    const int4* relI = (const int4*)relH;
    const int4* usrI = (const int4*)usrH;

    if (blockIdx.x < NEB) {
        // ================= entity path =================
        int node = blockIdx.x * 4 + w;
        U16 qh; qh.v = qmI[(long)node * 8 + li];
        int b0 = kg_off[node], b1 = kg_off[node + 1];
        int deg = b1 - b0;

        float ssum = 0.f;
        float acc[8] = {0.f, 0.f, 0.f, 0.f, 0.f, 0.f, 0.f, 0.f};
        if (deg > 0) {
            int s = b0;
            int i0 = s + sub;
            unsigned tr = kg_tr[i0 < b1 ? i0 : b1 - 1];
            for (; s < b1; s += 8) {
                int ni = s + 8 + sub;
                unsigned trn = kg_tr[ni < b1 ? ni : b1 - 1];  // prefetch next step's payload
                bool has = (s + sub) < b1;
                int tl = tr & 0x1FFFF, rr = (tr >> 17) & 15;
                U16 rl; rl.v = relI[rr * 8 + li];
                U16 qt; qt.v = qmI[(long)tl * 8 + li];
                U16 ev; ev.v = entI[(long)tl * 8 + li];
                float p = 0.f;
#pragma unroll
                for (int k = 0; k < 4; k++) {
                    __half2 kk = __hmul2(qt.h[k], rl.h[k]);
                    p = fdot2a(qh.h[k], kk, p);
                }
                p = dpp_red4(p);
                float e = __expf(has ? p * SC : NEG);
                ssum += e;
#pragma unroll
                for (int k = 0; k < 4; k++) {
                    __half2 v2 = __hmul2(ev.h[k], rl.h[k]);
                    float2 vf = __half22float2(v2);
                    acc[2 * k]     += vf.x * e;
                    acc[2 * k + 1] += vf.y * e;
                }
                tr = trn;
            }
#pragma unroll
            for (int o = 8; o <= 32; o <<= 1) {
                ssum += __shfl_xor(ssum, o, 64);
#pragma unroll
                for (int k = 0; k < 8; k++) acc[k] += __shfl_xor(acc[k], o, 64);
            }
            float inv = 1.f / ssum;
#pragma unroll
            for (int k = 0; k < 8; k++) acc[k] *= inv;
            float ss = 0.f;
#pragma unroll
            for (int k = 0; k < 8; k++) ss += acc[k] * acc[k];
            ss += __shfl_xor(ss, 1, 64);
            ss += __shfl_xor(ss, 2, 64);
            ss += __shfl_xor(ss, 4, 64);
            float nsc = 1.f / fmaxf(sqrtf(ss), 1e-12f);
#pragma unroll
            for (int k = 0; k < 8; k++) acc[k] *= nsc;
        }

        // user -> entity gather
        int c0 = iu_off[node], c1 = iu_off[node + 1];
        if (c1 > c0) {
            float ua[8] = {0.f, 0.f, 0.f, 0.f, 0.f, 0.f, 0.f, 0.f};
            int t2 = c0;
            int j0 = t2 + sub;
            int2 pw = iu_iw[j0 < c1 ? j0 : c1 - 1];
            for (; t2 < c1; t2 += 8) {
                int nj = t2 + 8 + sub;
                int2 pwn = iu_iw[nj < c1 ? nj : c1 - 1];
                bool has = (t2 + sub) < c1;
                float wv = has ? __int_as_float(pw.y) : 0.f;
                U16 uu; uu.v = usrI[(long)(pw.x & 0xFFFF) * 8 + li];
#pragma unroll
                for (int k = 0; k < 4; k++) {
                    float2 uf = __half22float2(uu.h[k]);
                    ua[2 * k]     += wv * uf.x;
                    ua[2 * k + 1] += wv * uf.y;
                }
                pw = pwn;
            }
#pragma unroll
            for (int o = 8; o <= 32; o <<= 1) {
#pragma unroll
                for (int k = 0; k < 8; k++) ua[k] += __shfl_xor(ua[k], o, 64);
            }
#pragma unroll
            for (int k = 0; k < 8; k++) acc[k] += ua[k];
        }

        if (sub == 0) {
            long base = (long)node * 16 + 2 * li;
            float4* eacc4 = (float4*)eacc;
            float4 e0, e1;
            if (FIRST) {
                e0.x = acc[0]; e0.y = acc[1]; e0.z = acc[2]; e0.w = acc[3];
                e1.x = acc[4]; e1.y = acc[5]; e1.z = acc[6]; e1.w = acc[7];
            } else {
                e0 = eacc4[base]; e1 = eacc4[base + 1];
                e0.x += acc[0]; e0.y += acc[1]; e0.z += acc[2]; e0.w += acc[3];
                e1.x += acc[4]; e1.y += acc[5]; e1.z += acc[6]; e1.w += acc[7];
            }
            if (!FINAL) {
                eacc4[base] = e0; eacc4[base + 1] = e1;
                U16 ho;
                ho.h[0] = __floats2half2_rn(acc[0], acc[1]);
                ho.h[1] = __floats2half2_rn(acc[2], acc[3]);
                ho.h[2] = __floats2half2_rn(acc[4], acc[5]);
                ho.h[3] = __floats2half2_rn(acc[6], acc[7]);
                ((int4*)entHout)[(long)node * 8 + li] = ho.v;
            } else {
                const float4* a4 = (const float4*)ent0;
                float4 a0 = a4[base], a1 = a4[base + 1];
                float4 o0, o1;
                o0.x = (a0.x + e0.x) * inv3; o0.y = (a0.y + e0.y) * inv3;
                o0.z = (a0.z + e0.z) * inv3; o0.w = (a0.w + e0.w) * inv3;
                o1.x = (a1.x + e1.x) * inv3; o1.y = (a1.y + e1.y) * inv3;
                o1.z = (a1.z + e1.z) * inv3; o1.w = (a1.w + e1.w) * inv3;
                float4* oute = (float4*)out + (long)NU * 16;
                oute[base] = o0; oute[base + 1] = o1;
            }
        }
    } else {
        // ================= user path =================
        int node = (blockIdx.x - NEB) * 4 + w;
        int b0 = ui_off[node], b1 = ui_off[node + 1];
        float ax[8] = {0.f, 0.f, 0.f, 0.f, 0.f, 0.f, 0.f, 0.f};
        if (b1 > b0) {
            int s = b0;
            int j0 = s + sub;
            int2 pw = ui_iw[j0 < b1 ? j0 : b1 - 1];
            for (; s < b1; s += 8) {
                int nj = s + 8 + sub;
                int2 pwn = ui_iw[nj < b1 ? nj : b1 - 1];
                bool has = (s + sub) < b1;
                float wv = has ? __int_as_float(pw.y) : 0.f;
                U16 uu; uu.v = entI[(long)(pw.x & 0x1FFFF) * 8 + li];
#pragma unroll
                for (int k = 0; k < 4; k++) {
                    float2 uf = __half22float2(uu.h[k]);
                    ax[2 * k]     += wv * uf.x;
                    ax[2 * k + 1] += wv * uf.y;
                }
                pw = pwn;
            }
#pragma unroll
            for (int o = 8; o <= 32; o <<= 1) {
#pragma unroll
                for (int k = 0; k < 8; k++) ax[k] += __shfl_xor(ax[k], o, 64);
            }
        }
        if (sub == 0) {
            long base = (long)node * 16 + 2 * li;
            float4* uacc4 = (float4*)uacc;
            float4 u0, u1;
            if (FIRST) {
                u0.x = ax[0]; u0.y = ax[1]; u0.z = ax[2]; u0.w = ax[3];
                u1.x = ax[4]; u1.y = ax[5]; u1.z = ax[6]; u1.w = ax[7];
            } else {
                u0 = uacc4[base]; u1 = uacc4[base + 1];
                u0.x += ax[0]; u0.y += ax[1]; u0.z += ax[2]; u0.w += ax[3];
                u1.x += ax[4]; u1.y += ax[5]; u1.z += ax[6]; u1.w += ax[7];
            }
            if (!FINAL) {
                uacc4[base] = u0; uacc4[base + 1] = u1;
                U16 ho;
                ho.h[0] = __floats2half2_rn(ax[0], ax[1]);
                ho.h[1] = __floats2half2_rn(ax[2], ax[3]);
                ho.h[2] = __floats2half2_rn(ax[4], ax[5]);
                ho.h[3] = __floats2half2_rn(ax[6], ax[7]);
                ((int4*)usrHout)[(long)node * 8 + li] = ho.v;
            } else {
                const float4* a4 = (const float4*)usr0;
                float4 a0 = a4[base], a1 = a4[base + 1];
                float4 o0, o1;
                o0.x = (a0.x + u0.x) * inv3; o0.y = (a0.y + u0.y) * inv3;
                o0.z = (a0.z + u0.z) * inv3; o0.w = (a0.w + u0.w) * inv3;
                o1.x = (a1.x + u1.x) * inv3; o1.y = (a1.y + u1.y) * inv3;
                o1.z = (a1.z + u1.z) * inv3; o1.w = (a1.w + u1.w) * inv3;
                float4* outu = (float4*)out;
                outu[base] = o0; outu[base + 1] = o1;
            }
        }
    }
}

extern "C" void kernel_launch(void* const* d_in, const int* in_sizes, int n_in,
                              void* d_out, int out_size, void* d_ws, size_t ws_size,
                              hipStream_t stream) {
    const float* usr0  = (const float*)d_in[1];
    const float* ent0  = (const float*)d_in[2];
    const int*   inter = (const int*)d_in[3];
    const float* iwf   = (const float*)d_in[4];
    const int*   eidx  = (const int*)d_in[5];
    const int*   etype = (const int*)d_in[6];
    const float* relf  = (const float*)d_in[7];
    const float* wqf   = (const float*)d_in[8];
    float* out = (float*)d_out;

    const int* eh = eidx;
    const int* et = eidx + EKG;
    const int* iu = inter;
    const int* ii = inter + EIN;

    // ---- workspace layout (4B words) ----
    float* p = (float*)d_ws;
    float* eacc = p;  p += (long)NE * DIM;
    float* uacc = p;  p += (long)NU * DIM;
    __half* qmH   = (__half*)p;  p += (long)NE * DIM / 2;
    __half* entHa = (__half*)p;  p += (long)NE * DIM / 2;
    __half* entHb = (__half*)p;  p += (long)NE * DIM / 2;
    __half* usrHa = (__half*)p;  p += (long)NU * DIM / 2;
    __half* usrHb = (__half*)p;  p += (long)NU * DIM / 2;
    __half* relH  = (__half*)p;  p += (long)NRELS * DIM / 2;
    int* cntK = (int*)p;        p += 256;
    int* cntU = (int*)p;        p += 256;
    int* cntI = (int*)p;        p += 256;
    int* kg_boff = (int*)p;     p += 256;
    int* ui_boff = (int*)p;     p += 256;
    int* iu_boff = (int*)p;     p += 256;
    int* kg_off = (int*)p;      p += NE + 2;
    int* ui_off = (int*)p;      p += NU + 2;
    int* iu_off = (int*)p;      p += NE + 2;
    int* kg_g   = (int*)p;      p += 256;
    int* ui_g   = (int*)p;      p += 256;
    int* iu_g   = (int*)p;      p += 256;
    unsigned* kg_tr  = (unsigned*)p; p += EKG;
    unsigned* kg_tmp = (unsigned*)p; p += EKG;
    int2* ui_iw  = (int2*)p;    p += (long)EIN * 2;
    int2* ui_tmp = (int2*)p;    p += (long)EIN * 2;
    int2* iu_iw  = (int2*)p;    p += (long)EIN * 2;
    int2* iu_tmp = (int2*)p;    p += (long)EIN * 2;

    const int B = 256;

    // ---- init: bucket counters only (eacc/uacc written in store-mode) ----
    hipMemsetAsync(cntK, 0, (size_t)768 * 4, stream);
    k_castH<<<(NU * 16 + B - 1) / B, B, 0, stream>>>((const float4*)usr0, (const float4*)relf,
                                                     (int2*)usrHa, (int2*)relH);

    // ---- CSR build ----
    k_hist_bucket<<<512, 256, 0, stream>>>(eh, iu, ii, cntK, cntU, cntI);
    k_bucket_scan<<<1, 256, 0, stream>>>(cntK, cntU, cntI, kg_boff, ui_boff, iu_boff,
                                         kg_g, ui_g, iu_g);
    k_binB_all<<<NB_BKG + NB_B8 + NB_B8, 256, 0, stream>>>(eh, et, etype, kg_g, kg_tmp,
                                                           iu, ii, iwf,
                                                           ui_g, ui_tmp, iu_g, iu_tmp);
    k_binC_all<<<NB_CKG + NB_CUI + NB_CIU, 256, 0, stream>>>(kg_tmp, kg_boff, kg_tr, kg_off,
                                                             ui_tmp, ui_boff, ui_iw, ui_off,
                                                             iu_tmp, iu_boff, iu_iw, iu_off);

    // ---- layer 0 ----
    k_gemm_f<<<NE / 16, 256, 0, stream>>>(ent0, wqf, qmH, entHa);
    k_layer<true, false><<<NEB + NUB, 256, 0, stream>>>(qmH, relH, entHa, usrHa,
                                                        kg_off, kg_tr, iu_off, iu_iw,
                                                        ui_off, ui_iw,
                                                        eacc, entHb, uacc, usrHb,
                                                        nullptr, nullptr, nullptr);
    // ---- layer 1 (folds k_final) ----
    k_gemm_h<<<NE / 16, 256, 0, stream>>>(entHb, wqf, qmH);
    k_layer<false, true><<<NEB + NUB, 256, 0, stream>>>(qmH, relH, entHb, usrHb,
                                                        kg_off, kg_tr, iu_off, iu_iw,
                                                        ui_off, ui_iw,
                                                        eacc, nullptr, uacc, nullptr,
                                                        ent0, usr0, out);
}

// Round 10
// 467.182 us; speedup vs baseline: 1.0859x; 1.0152x over previous
//
#include <hip/hip_runtime.h>
#include <hip/hip_fp16.h>

#define NU 50000
#define NE 100000
#define DIM 64
#define NRELS 16
#define EKG 1500000
#define EIN 1000000

#define KG_CHUNK 8192
#define KG_NBUCK ((NE + 511) >> 9)   // 196
#define B8_CHUNK 4096
#define KG_CAP 9216
#define C8_CAP 6656

#define NEB (NE / 4)                 // 25000 ent blocks
#define NUB (NU / 4)                 // 12500 usr blocks

#define NB_BKG ((EKG + KG_CHUNK - 1) / KG_CHUNK)   // 184
#define NB_B8  ((EIN + B8_CHUNK - 1) / B8_CHUNK)   // 245
#define NB_CKG KG_NBUCK                             // 196
#define NB_CUI ((NU + 255) >> 8)                    // 196
#define NB_CIU ((NE + 511) >> 9)                    // 196

#define NB_PREP_H 512
#define NB_PREP_C 3125                              // (NU*16)/256
#define NB_PREP_G (NE / 16)                         // 6250

typedef _Float16 f16x2 __attribute__((ext_vector_type(2)));

union U16 { int4 v; __half2 h[4]; };
union H4 { int2 i2; __half2 h[2]; };

__device__ __forceinline__ float fdot2a(__half2 a, __half2 b, float c) {
#if __has_builtin(__builtin_amdgcn_fdot2)
    union { __half2 h; f16x2 v; } ua, ub;
    ua.h = a; ub.h = b;
    return __builtin_amdgcn_fdot2(ua.v, ub.v, c, false);
#else
    return c + __half2float(a.x) * __half2float(b.x) + __half2float(a.y) * __half2float(b.y);
#endif
}

// sum over each 4-lane quad via DPP (score reduce; head = quad)
__device__ __forceinline__ float dpp_red4(float p) {
    int t;
    t = __builtin_amdgcn_update_dpp(0, __float_as_int(p), 0xB1, 0xF, 0xF, true);  // quad_perm xor1
    p += __int_as_float(t);
    t = __builtin_amdgcn_update_dpp(0, __float_as_int(p), 0x4E, 0xF, 0xF, true);  // quad_perm xor2
    p += __int_as_float(t);
    return p;
}

// ---- merged prep: blocks [0,512) hist, [512,3637) usr/rel cast, [3637,9887) gemm_f+ent cast
struct SmP {
    union {
        struct { int sK[256], sU[256], sI[256]; } h;
        struct { float sW[64 * 64]; float sR[16 * 64]; } g;
    } u;
};

__global__ __launch_bounds__(256) void k_prep(const int* __restrict__ eh,
        const int* __restrict__ iu, const int* __restrict__ ii,
        int* __restrict__ cntK, int* __restrict__ cntU, int* __restrict__ cntI,
        const float4* __restrict__ u4, const float4* __restrict__ r4,
        int2* __restrict__ uH, int2* __restrict__ rH,
        const float* __restrict__ ent, const float* __restrict__ wq,
        __half* __restrict__ qmH, __half* __restrict__ entH) {
    __shared__ SmP sm;
    int bid = blockIdx.x;
    int t = threadIdx.x;
    if (bid < NB_PREP_H) {
        // ---- bucket-level histogram (LDS-privatized) ----
        sm.u.h.sK[t] = 0; sm.u.h.sU[t] = 0; sm.u.h.sI[t] = 0;
        __syncthreads();
        int stride = NB_PREP_H * 256;
        for (int e = bid * 256 + t; e < EKG; e += stride)
            atomicAdd(&sm.u.h.sK[eh[e] >> 9], 1);
        for (int e = bid * 256 + t; e < EIN; e += stride) {
            atomicAdd(&sm.u.h.sU[iu[e] >> 8], 1);
            atomicAdd(&sm.u.h.sI[ii[e] >> 9], 1);
        }
        __syncthreads();
        if (sm.u.h.sK[t]) atomicAdd(&cntK[t], sm.u.h.sK[t]);
        if (sm.u.h.sU[t]) atomicAdd(&cntU[t], sm.u.h.sU[t]);
        if (sm.u.h.sI[t]) atomicAdd(&cntI[t], sm.u.h.sI[t]);
    } else if (bid < NB_PREP_H + NB_PREP_C) {
        // ---- fp16 cast for usr + rel ----
        int i = (bid - NB_PREP_H) * 256 + t;
        if (i < NU * 16) {
            float4 v = u4[i];
            H4 o; o.h[0] = __floats2half2_rn(v.x, v.y); o.h[1] = __floats2half2_rn(v.z, v.w);
            uH[i] = o.i2;
        }
        if (i < NRELS * 16) {
            float4 v = r4[i];
            H4 o; o.h[0] = __floats2half2_rn(v.x, v.y); o.h[1] = __floats2half2_rn(v.z, v.w);
            rH[i] = o.i2;
        }
    } else {
        // ---- qm = ent0 @ WQ -> fp16, plus ent0 -> fp16 mirror ----
        for (int i = t; i < 4096; i += 256) sm.u.g.sW[i] = wq[i];
        long row0 = (long)(bid - NB_PREP_H - NB_PREP_C) * 16;
        for (int i = t; i < 1024; i += 256) sm.u.g.sR[i] = ent[row0 * 64 + i];
        __syncthreads();
        int r = t >> 4, cg = t & 15;
        const float4* sW4 = (const float4*)sm.u.g.sW;
        const float4* sR4 = (const float4*)sm.u.g.sR;
        float4 acc = {0.f, 0.f, 0.f, 0.f};
#pragma unroll
        for (int k = 0; k < 64; k++) {
            float a = sm.u.g.sR[r * 64 + k];
            float4 wv = sW4[k * 16 + cg];
            acc.x += a * wv.x; acc.y += a * wv.y; acc.z += a * wv.z; acc.w += a * wv.w;
        }
        H4 o;
        o.h[0] = __floats2half2_rn(acc.x, acc.y);
        o.h[1] = __floats2half2_rn(acc.z, acc.w);
        ((int2*)qmH)[(row0 + r) * 16 + cg] = o.i2;
        float4 ev = sR4[r * 16 + cg];
        H4 e;
        e.h[0] = __floats2half2_rn(ev.x, ev.y);
        e.h[1] = __floats2half2_rn(ev.z, ev.w);
        ((int2*)entH)[(row0 + r) * 16 + cg] = e.i2;
    }
}

// layer-1 gemm: fp16 ent input
__global__ __launch_bounds__(256) void k_gemm_h(const __half* __restrict__ ent,
                                                const float* __restrict__ wq,
                                                __half* __restrict__ qmH) {
    __shared__ float sW[64 * 64];
    __shared__ float sR[16 * 64];
    int t = threadIdx.x;
    for (int i = t; i < 4096; i += 256) sW[i] = wq[i];
    long row0 = (long)blockIdx.x * 16;
    const __half2* e2 = (const __half2*)ent;
    for (int i = t; i < 512; i += 256) {
        float2 f = __half22float2(e2[row0 * 32 + i]);
        sR[2 * i] = f.x; sR[2 * i + 1] = f.y;
    }
    __syncthreads();
    int r = t >> 4, cg = t & 15;
    const float4* sW4 = (const float4*)sW;
    float4 acc = {0.f, 0.f, 0.f, 0.f};
#pragma unroll
    for (int k = 0; k < 64; k++) {
        float a = sR[r * 64 + k];
        float4 wv = sW4[k * 16 + cg];
        acc.x += a * wv.x; acc.y += a * wv.y; acc.z += a * wv.z; acc.w += a * wv.w;
    }
    H4 o;
    o.h[0] = __floats2half2_rn(acc.x, acc.y);
    o.h[1] = __floats2half2_rn(acc.z, acc.w);
    ((int2*)qmH)[(row0 + r) * 16 + cg] = o.i2;
}

// ---- tiny scans: bucket counts -> bucket offsets + gcur init ----
__global__ __launch_bounds__(256) void k_bucket_scan(const int* __restrict__ cntK,
        const int* __restrict__ cntU, const int* __restrict__ cntI,
        int* __restrict__ kg_boff, int* __restrict__ ui_boff, int* __restrict__ iu_boff,
        int* __restrict__ kg_g, int* __restrict__ ui_g, int* __restrict__ iu_g) {
    __shared__ int sc[256];
    int t = threadIdx.x;
#define SCAN1(cnt, boff, gcur) { \
    int v = cnt[t]; sc[t] = v; __syncthreads(); \
    for (int o = 1; o < 256; o <<= 1) { \
        int u = (t >= o) ? sc[t - o] : 0; __syncthreads(); sc[t] += u; __syncthreads(); } \
    int e = sc[t] - v; boff[t] = e; gcur[t] = e; \
    __syncthreads(); }
    SCAN1(cntK, kg_boff, kg_g)
    SCAN1(cntU, ui_boff, ui_g)
    SCAN1(cntI, iu_boff, iu_g)
#undef SCAN1
}

// ---- merged pass B ----
struct SmB {
    union {
        struct { unsigned stage[KG_CHUNK]; int dest[KG_CHUNK]; } kg;
        struct { int2 stage[B8_CHUNK]; int dest[B8_CHUNK]; } b8;
    } u;
};

__device__ __forceinline__ void binB8_body(const int* __restrict__ key,
        const int* __restrict__ aux, const float* __restrict__ wv, int nE,
        int shift, int auxShift, int* __restrict__ gcur, int2* __restrict__ tmp,
        int cb, int2* stage, int* dest,
        int* cnt, int* boff, int* gbase, int* curl, int* sc) {
    int t = threadIdx.x;
    int base = cb * B8_CHUNK;
    int nloc = nE - base; if (nloc > B8_CHUNK) nloc = B8_CHUNK;
    cnt[t] = 0;
    __syncthreads();
    for (int i = t; i < nloc; i += 256)
        atomicAdd(&cnt[key[base + i] >> shift], 1);
    __syncthreads();
    int v = cnt[t];
    sc[t] = v;
    __syncthreads();
    for (int o = 1; o < 256; o <<= 1) {
        int u = (t >= o) ? sc[t - o] : 0;
        __syncthreads();
        sc[t] += u;
        __syncthreads();
    }
    boff[t] = sc[t] - v;
    curl[t] = sc[t] - v;
    gbase[t] = atomicAdd(&gcur[t], v);
    __syncthreads();
    int lowmask = (1 << shift) - 1;
    for (int i = t; i < nloc; i += 256) {
        int e = base + i;
        int k = key[e];
        int b = k >> shift;
        int2 pay;
        pay.x = aux[e] | ((k & lowmask) << auxShift);
        pay.y = __float_as_int(wv[e]);
        int pos = atomicAdd(&curl[b], 1);
        stage[pos] = pay;
        dest[pos] = gbase[b] + (pos - boff[b]);
    }
    __syncthreads();
    for (int s = t; s < nloc; s += 256) tmp[dest[s]] = stage[s];
}

__global__ __launch_bounds__(256) void k_binB_all(const int* __restrict__ eh,
        const int* __restrict__ et, const int* __restrict__ ety,
        int* __restrict__ kg_g, unsigned* __restrict__ kg_tmp,
        const int* __restrict__ iu, const int* __restrict__ ii,
        const float* __restrict__ iwf,
        int* __restrict__ ui_g, int2* __restrict__ ui_tmp,
        int* __restrict__ iu_g, int2* __restrict__ iu_tmp) {
    __shared__ SmB sm;
    __shared__ int cnt[256], boff[256], gbase[256], curl[256], sc[256];
    int bid = blockIdx.x;
    int t = threadIdx.x;
    if (bid < NB_BKG) {
        int base = bid * KG_CHUNK;
        int nloc = EKG - base; if (nloc > KG_CHUNK) nloc = KG_CHUNK;
        for (int i = t; i < KG_NBUCK; i += 256) cnt[i] = 0;
        __syncthreads();
        for (int i = t; i < nloc; i += 256)
            atomicAdd(&cnt[eh[base + i] >> 9], 1);
        __syncthreads();
        int v = (t < KG_NBUCK) ? cnt[t] : 0;
        sc[t] = v;
        __syncthreads();
        for (int o = 1; o < 256; o <<= 1) {
            int u = (t >= o) ? sc[t - o] : 0;
            __syncthreads();
            sc[t] += u;
            __syncthreads();
        }
        if (t < KG_NBUCK) {
            boff[t] = sc[t] - v;
            curl[t] = sc[t] - v;
            gbase[t] = atomicAdd(&kg_g[t], v);
        }
        __syncthreads();
        for (int i = t; i < nloc; i += 256) {
            int e = base + i;
            int h = eh[e];
            int b = h >> 9;
            unsigned pay = (unsigned)et[e] | ((unsigned)(ety[e] - 1) << 17)
                         | ((unsigned)(h & 511) << 21);
            int pos = atomicAdd(&curl[b], 1);
            sm.u.kg.stage[pos] = pay;
            sm.u.kg.dest[pos] = gbase[b] + (pos - boff[b]);
        }
        __syncthreads();
        for (int s = t; s < nloc; s += 256) kg_tmp[sm.u.kg.dest[s]] = sm.u.kg.stage[s];
    } else if (bid < NB_BKG + NB_B8) {
        binB8_body(iu, ii, iwf, EIN, 8, 17, ui_g, ui_tmp, bid - NB_BKG,
                   sm.u.b8.stage, sm.u.b8.dest, cnt, boff, gbase, curl, sc);
    } else {
        binB8_body(ii, iu, iwf, EIN, 9, 16, iu_g, iu_tmp, bid - NB_BKG - NB_B8,
                   sm.u.b8.stage, sm.u.b8.dest, cnt, boff, gbase, curl, sc);
    }
}

// ---- merged pass C ----
struct SmC {
    union {
        unsigned kgstage[KG_CAP];
        int2 c8stage[C8_CAP];
    } u;
};

__device__ __forceinline__ void binC8_body(const int2* __restrict__ tmp,
        const int* __restrict__ boffg, int2* __restrict__ dst, int* __restrict__ off,
        int nnodes, int shift, int auxShift, int lb, int nb,
        int2* stage, int* curl, int* sc) {
    int b = lb;
    int nbase = b << shift;
    int nlim = nnodes - nbase; if (nlim > (1 << shift)) nlim = 1 << shift;
    if (nlim <= 0) return;
    int t = threadIdx.x;
    int r0 = boffg[b];
    int r1 = boffg[b + 1];
    int cntb = r1 - r0;
    int lowmask = (1 << shift) - 1;
    curl[t] = 0; curl[t + 256] = 0;
    __syncthreads();
    for (int s = t; s < cntb; s += 256)
        atomicAdd(&curl[(tmp[r0 + s].x >> auxShift) & lowmask], 1);
    __syncthreads();
    int v0 = curl[2 * t], v1 = curl[2 * t + 1];
    int s2 = v0 + v1;
    sc[t] = s2;
    __syncthreads();
    for (int o = 1; o < 256; o <<= 1) {
        int u = (t >= o) ? sc[t - o] : 0;
        __syncthreads();
        sc[t] += u;
        __syncthreads();
    }
    int excl = sc[t] - s2;
    curl[2 * t] = excl;
    curl[2 * t + 1] = excl + v0;
    if (2 * t < nlim) off[nbase + 2 * t] = r0 + excl;
    if (2 * t + 1 < nlim) off[nbase + 2 * t + 1] = r0 + excl + v0;
    if (b == nb - 1 && t == 0) off[nbase + nlim] = r1;  // sentinel
    __syncthreads();
    if (cntb <= C8_CAP) {
        for (int s = t; s < cntb; s += 256) {
            int2 pay = tmp[r0 + s];
            int l = (pay.x >> auxShift) & lowmask;
            int pos = atomicAdd(&curl[l], 1);
            stage[pos] = pay;
        }
        __syncthreads();
        for (int s = t; s < cntb; s += 256) dst[r0 + s] = stage[s];
    } else {
        for (int s = t; s < cntb; s += 256) {
            int2 pay = tmp[r0 + s];
            int l = (pay.x >> auxShift) & lowmask;
            int pos = atomicAdd(&curl[l], 1);
            dst[r0 + pos] = pay;
        }
    }
}

__global__ __launch_bounds__(256) void k_binC_all(const unsigned* __restrict__ kg_tmp,
        const int* __restrict__ kg_boff, unsigned* __restrict__ kg_tr, int* __restrict__ kg_off,
        const int2* __restrict__ ui_tmp, const int* __restrict__ ui_boff,
        int2* __restrict__ ui_iw, int* __restrict__ ui_off,
        const int2* __restrict__ iu_tmp, const int* __restrict__ iu_boff,
        int2* __restrict__ iu_iw, int* __restrict__ iu_off) {
    __shared__ SmC sm;
    __shared__ int curl[512];
    __shared__ int sc[256];
    int bid = blockIdx.x;
    int t = threadIdx.x;
    if (bid < NB_CKG) {
        int b = bid;
        int nbase = b << 9;
        int nlim = NE - nbase; if (nlim > 512) nlim = 512;
        if (nlim <= 0) return;
        int r0 = kg_boff[b];
        int r1 = kg_boff[b + 1];
        int cntb = r1 - r0;
        curl[t] = 0; curl[t + 256] = 0;
        __syncthreads();
        for (int s = t; s < cntb; s += 256)
            atomicAdd(&curl[(kg_tmp[r0 + s] >> 21) & 511], 1);
        __syncthreads();
        int v0 = curl[2 * t], v1 = curl[2 * t + 1];
        int s2 = v0 + v1;
        sc[t] = s2;
        __syncthreads();
        for (int o = 1; o < 256; o <<= 1) {
            int u = (t >= o) ? sc[t - o] : 0;
            __syncthreads();
            sc[t] += u;
            __syncthreads();
        }
        int excl = sc[t] - s2;
        curl[2 * t] = excl;
        curl[2 * t + 1] = excl + v0;
        if (2 * t < nlim) kg_off[nbase + 2 * t] = r0 + excl;
        if (2 * t + 1 < nlim) kg_off[nbase + 2 * t + 1] = r0 + excl + v0;
        if (b == NB_CKG - 1 && t == 0) kg_off[nbase + nlim] = r1;   // sentinel off[NE]
        __syncthreads();
        if (cntb <= KG_CAP) {
            for (int s = t; s < cntb; s += 256) {
                unsigned pay = kg_tmp[r0 + s];
                int l = (pay >> 21) & 511;
                int pos = atomicAdd(&curl[l], 1);
                sm.u.kgstage[pos] = pay;
            }
            __syncthreads();
            for (int s = t; s < cntb; s += 256) kg_tr[r0 + s] = sm.u.kgstage[s];
        } else {
            for (int s = t; s < cntb; s += 256) {
                unsigned pay = kg_tmp[r0 + s];
                int l = (pay >> 21) & 511;
                int pos = atomicAdd(&curl[l], 1);
                kg_tr[r0 + pos] = pay;
            }
        }
    } else if (bid < NB_CKG + NB_CUI) {
        binC8_body(ui_tmp, ui_boff, ui_iw, ui_off, NU, 8, 17,
                   bid - NB_CKG, NB_CUI, sm.u.c8stage, curl, sc);
    } else {
        binC8_body(iu_tmp, iu_boff, iu_iw, iu_off, NE, 9, 16,
                   bid - NB_CKG - NB_CUI, NB_CIU, sm.u.c8stage, curl, sc);
    }
}

// ---- fused per-layer kernel. Value/user accumulation now in packed f16
// (__hfma2): scores ~1e-3 so e~=1; f16 accumulate over <=50 edges adds <=3e-3
// absolute (6x headroom). Sub-chain merges / softmax / normalize stay f32.
// FIRST=true: eacc/uacc stores; FINAL=true: folds k_final epilogue.
template<bool FIRST, bool FINAL>
__global__ __launch_bounds__(256) void k_layer(const __half* __restrict__ qmH,
        const __half* __restrict__ relH, const __half* __restrict__ entH,
        const __half* __restrict__ usrH,
        const int* __restrict__ kg_off, const unsigned* __restrict__ kg_tr,
        const int* __restrict__ iu_off, const int2* __restrict__ iu_iw,
        const int* __restrict__ ui_off, const int2* __restrict__ ui_iw,
        float* __restrict__ eacc, __half* __restrict__ entHout,
        float* __restrict__ uacc, __half* __restrict__ usrHout,
        const float* __restrict__ ent0, const float* __restrict__ usr0,
        float* __restrict__ out) {
    int w = __builtin_amdgcn_readfirstlane(threadIdx.x >> 6);
    int lane = threadIdx.x & 63;
    int sub = lane >> 3;          // edge slot 0..7
    int li  = lane & 7;           // dims 8li..8li+7
    const float SC = 0.17677669529663687f; // 1/sqrt(32)
    const float NEG = -1e30f;
    const float inv3 = 1.f / 3.f;
    const int4* qmI  = (const int4*)qmH;
    const int4* entI = (const int4*)entH;
    const int4* relI = (const int4*)relH;
    const int4* usrI = (const int4*)usrH;
    const __half2 hz = __floats2half2_rn(0.f, 0.f);

    if (blockIdx.x < NEB) {
        // ================= entity path =================
        int node = blockIdx.x * 4 + w;
        U16 qh; qh.v = qmI[(long)node * 8 + li];
        int b0 = kg_off[node], b1 = kg_off[node + 1];
        int deg = b1 - b0;

        float ssum = 0.f;
        float acc[8] = {0.f, 0.f, 0.f, 0.f, 0.f, 0.f, 0.f, 0.f};
        if (deg > 0) {
            __half2 acc_h[4] = {hz, hz, hz, hz};
            int s = b0;
            int i0 = s + sub;
            unsigned tr = kg_tr[i0 < b1 ? i0 : b1 - 1];
            for (; s < b1; s += 8) {
                int ni = s + 8 + sub;
                unsigned trn = kg_tr[ni < b1 ? ni : b1 - 1];  // prefetch next step's payload
                bool has = (s + sub) < b1;
                int tl = tr & 0x1FFFF, rr = (tr >> 17) & 15;
                U16 rl; rl.v = relI[rr * 8 + li];
                U16 qt; qt.v = qmI[(long)tl * 8 + li];
                U16 ev; ev.v = entI[(long)tl * 8 + li];
                float p = 0.f;
#pragma unroll
                for (int k = 0; k < 4; k++) {
                    __half2 kk = __hmul2(qt.h[k], rl.h[k]);
                    p = fdot2a(qh.h[k], kk, p);
                }
                p = dpp_red4(p);
                float e = __expf(has ? p * SC : NEG);
                ssum += e;
                __half2 e2 = __float2half2_rn(e);
#pragma unroll
                for (int k = 0; k < 4; k++)
                    acc_h[k] = __hfma2(__hmul2(ev.h[k], rl.h[k]), e2, acc_h[k]);
                tr = trn;
            }
#pragma unroll
            for (int k = 0; k < 4; k++) {
                float2 vf = __half22float2(acc_h[k]);
                acc[2 * k] = vf.x; acc[2 * k + 1] = vf.y;
            }
#pragma unroll
            for (int o = 8; o <= 32; o <<= 1) {
                ssum += __shfl_xor(ssum, o, 64);
#pragma unroll
                for (int k = 0; k < 8; k++) acc[k] += __shfl_xor(acc[k], o, 64);
            }
            float inv = 1.f / ssum;
#pragma unroll
            for (int k = 0; k < 8; k++) acc[k] *= inv;
            float ss = 0.f;
#pragma unroll
            for (int k = 0; k < 8; k++) ss += acc[k] * acc[k];
            ss += __shfl_xor(ss, 1, 64);
            ss += __shfl_xor(ss, 2, 64);
            ss += __shfl_xor(ss, 4, 64);
            float nsc = 1.f / fmaxf(sqrtf(ss), 1e-12f);
#pragma unroll
            for (int k = 0; k < 8; k++) acc[k] *= nsc;
        }

        // user -> entity gather (f16 packed accumulate)
        int c0 = iu_off[node], c1 = iu_off[node + 1];
        if (c1 > c0) {
            __half2 ua_h[4] = {hz, hz, hz, hz};
            int t2 = c0;
            int j0 = t2 + sub;
            int2 pw = iu_iw[j0 < c1 ? j0 : c1 - 1];
            for (; t2 < c1; t2 += 8) {
                int nj = t2 + 8 + sub;
                int2 pwn = iu_iw[nj < c1 ? nj : c1 - 1];
                bool has = (t2 + sub) < c1;
                float wv = has ? __int_as_float(pw.y) : 0.f;
                __half2 wv2 = __float2half2_rn(wv);
                U16 uu; uu.v = usrI[(long)(pw.x & 0xFFFF) * 8 + li];
#pragma unroll
                for (int k = 0; k < 4; k++)
                    ua_h[k] = __hfma2(uu.h[k], wv2, ua_h[k]);
                pw = pwn;
            }
            float ua[8];
#pragma unroll
            for (int k = 0; k < 4; k++) {
                float2 uf = __half22float2(ua_h[k]);
                ua[2 * k] = uf.x; ua[2 * k + 1] = uf.y;
            }
#pragma unroll
            for (int o = 8; o <= 32; o <<= 1) {
#pragma unroll
                for (int k = 0; k < 8; k++) ua[k] += __shfl_xor(ua[k], o, 64);
            }
#pragma unroll
            for (int k = 0; k < 8; k++) acc[k] += ua[k];
        }

        if (sub == 0) {
            long base = (long)node * 16 + 2 * li;
            float4* eacc4 = (float4*)eacc;
            float4 e0, e1;
            if (FIRST) {
                e0.x = acc[0]; e0.y = acc[1]; e0.z = acc[2]; e0.w = acc[3];
                e1.x = acc[4]; e1.y = acc[5]; e1.z = acc[6]; e1.w = acc[7];
            } else {
                e0 = eacc4[base]; e1 = eacc4[base + 1];
                e0.x += acc[0]; e0.y += acc[1]; e0.z += acc[2]; e0.w += acc[3];
                e1.x += acc[4]; e1.y += acc[5]; e1.z += acc[6]; e1.w += acc[7];
            }
            if (!FINAL) {
                eacc4[base] = e0; eacc4[base + 1] = e1;
                U16 ho;
                ho.h[0] = __floats2half2_rn(acc[0], acc[1]);
                ho.h[1] = __floats2half2_rn(acc[2], acc[3]);
                ho.h[2] = __floats2half2_rn(acc[4], acc[5]);
                ho.h[3] = __floats2half2_rn(acc[6], acc[7]);
                ((int4*)entHout)[(long)node * 8 + li] = ho.v;
            } else {
                const float4* a4 = (const float4*)ent0;
                float4 a0 = a4[base], a1 = a4[base + 1];
                float4 o0, o1;
                o0.x = (a0.x + e0.x) * inv3; o0.y = (a0.y + e0.y) * inv3;
                o0.z = (a0.z + e0.z) * inv3; o0.w = (a0.w + e0.w) * inv3;
                o1.x = (a1.x + e1.x) * inv3; o1.y = (a1.y + e1.y) * inv3;
                o1.z = (a1.z + e1.z) * inv3; o1.w = (a1.w + e1.w) * inv3;
                float4* oute = (float4*)out + (long)NU * 16;
                oute[base] = o0; oute[base + 1] = o1;
            }
        }
    } else {
        // ================= user path (f16 packed accumulate) =================
        int node = (blockIdx.x - NEB) * 4 + w;
        int b0 = ui_off[node], b1 = ui_off[node + 1];
        float ax[8] = {0.f, 0.f, 0.f, 0.f, 0.f, 0.f, 0.f, 0.f};
        if (b1 > b0) {
            __half2 ax_h[4] = {hz, hz, hz, hz};
            int s = b0;
            int j0 = s + sub;
            int2 pw = ui_iw[j0 < b1 ? j0 : b1 - 1];
            for (; s < b1; s += 8) {
                int nj = s + 8 + sub;
                int2 pwn = ui_iw[nj < b1 ? nj : b1 - 1];
                bool has = (s + sub) < b1;
                float wv = has ? __int_as_float(pw.y) : 0.f;
                __half2 wv2 = __float2half2_rn(wv);
                U16 uu; uu.v = entI[(long)(pw.x & 0x1FFFF) * 8 + li];
#pragma unroll
                for (int k = 0; k < 4; k++)
                    ax_h[k] = __hfma2(uu.h[k], wv2, ax_h[k]);
                pw = pwn;
            }
#pragma unroll
            for (int k = 0; k < 4; k++) {
                float2 uf = __half22float2(ax_h[k]);
                ax[2 * k] = uf.x; ax[2 * k + 1] = uf.y;
            }
#pragma unroll
            for (int o = 8; o <= 32; o <<= 1) {
#pragma unroll
                for (int k = 0; k < 8; k++) ax[k] += __shfl_xor(ax[k], o, 64);
            }
        }
        if (sub == 0) {
            long base = (long)node * 16 + 2 * li;
            float4* uacc4 = (float4*)uacc;
            float4 u0, u1;
            if (FIRST) {
                u0.x = ax[0]; u0.y = ax[1]; u0.z = ax[2]; u0.w = ax[3];
                u1.x = ax[4]; u1.y = ax[5]; u1.z = ax[6]; u1.w = ax[7];
            } else {
                u0 = uacc4[base]; u1 = uacc4[base + 1];
                u0.x += ax[0]; u0.y += ax[1]; u0.z += ax[2]; u0.w += ax[3];
                u1.x += ax[4]; u1.y += ax[5]; u1.z += ax[6]; u1.w += ax[7];
            }
            if (!FINAL) {
                uacc4[base] = u0; uacc4[base + 1] = u1;
                U16 ho;
                ho.h[0] = __floats2half2_rn(ax[0], ax[1]);
                ho.h[1] = __floats2half2_rn(ax[2], ax[3]);
                ho.h[2] = __floats2half2_rn(ax[4], ax[5]);
                ho.h[3] = __floats2half2_rn(ax[6], ax[7]);
                ((int4*)usrHout)[(long)node * 8 + li] = ho.v;
            } else {
                const float4* a4 = (const float4*)usr0;
                float4 a0 = a4[base], a1 = a4[base + 1];
                float4 o0, o1;
                o0.x = (a0.x + u0.x) * inv3; o0.y = (a0.y + u0.y) * inv3;
                o0.z = (a0.z + u0.z) * inv3; o0.w = (a0.w + u0.w) * inv3;
                o1.x = (a1.x + u1.x) * inv3; o1.y = (a1.y + u1.y) * inv3;
                o1.z = (a1.z + u1.z) * inv3; o1.w = (a1.w + u1.w) * inv3;
                float4* outu = (float4*)out;
                outu[base] = o0; outu[base + 1] = o1;
            }
        }
    }
}

extern "C" void kernel_launch(void* const* d_in, const int* in_sizes, int n_in,
                              void* d_out, int out_size, void* d_ws, size_t ws_size,
                              hipStream_t stream) {
    const float* usr0  = (const float*)d_in[1];
    const float* ent0  = (const float*)d_in[2];
    const int*   inter = (const int*)d_in[3];
    const float* iwf   = (const float*)d_in[4];
    const int*   eidx  = (const int*)d_in[5];
    const int*   etype = (const int*)d_in[6];
    const float* relf  = (const float*)d_in[7];
    const float* wqf   = (const float*)d_in[8];
    float* out = (float*)d_out;

    const int* eh = eidx;
    const int* et = eidx + EKG;
    const int* iu = inter;
    const int* ii = inter + EIN;

    // ---- workspace layout (4B words) ----
    float* p = (float*)d_ws;
    float* eacc = p;  p += (long)NE * DIM;
    float* uacc = p;  p += (long)NU * DIM;
    __half* qmH   = (__half*)p;  p += (long)NE * DIM / 2;
    __half* entHa = (__half*)p;  p += (long)NE * DIM / 2;
    __half* entHb = (__half*)p;  p += (long)NE * DIM / 2;
    __half* usrHa = (__half*)p;  p += (long)NU * DIM / 2;
    __half* usrHb = (__half*)p;  p += (long)NU * DIM / 2;
    __half* relH  = (__half*)p;  p += (long)NRELS * DIM / 2;
    int* cntK = (int*)p;        p += 256;
    int* cntU = (int*)p;        p += 256;
    int* cntI = (int*)p;        p += 256;
    int* kg_boff = (int*)p;     p += 256;
    int* ui_boff = (int*)p;     p += 256;
    int* iu_boff = (int*)p;     p += 256;
    int* kg_off = (int*)p;      p += NE + 2;
    int* ui_off = (int*)p;      p += NU + 2;
    int* iu_off = (int*)p;      p += NE + 2;
    int* kg_g   = (int*)p;      p += 256;
    int* ui_g   = (int*)p;      p += 256;
    int* iu_g   = (int*)p;      p += 256;
    unsigned* kg_tr  = (unsigned*)p; p += EKG;
    unsigned* kg_tmp = (unsigned*)p; p += EKG;
    int2* ui_iw  = (int2*)p;    p += (long)EIN * 2;
    int2* ui_tmp = (int2*)p;    p += (long)EIN * 2;
    int2* iu_iw  = (int2*)p;    p += (long)EIN * 2;
    int2* iu_tmp = (int2*)p;    p += (long)EIN * 2;

    // ---- init: bucket counters only ----
    hipMemsetAsync(cntK, 0, (size_t)768 * 4, stream);

    // ---- prep: hist + usr/rel cast + gemm_f (independent; one dispatch) ----
    k_prep<<<NB_PREP_H + NB_PREP_C + NB_PREP_G, 256, 0, stream>>>(
        eh, iu, ii, cntK, cntU, cntI,
        (const float4*)usr0, (const float4*)relf, (int2*)usrHa, (int2*)relH,
        ent0, wqf, qmH, entHa);

    // ---- CSR build ----
    k_bucket_scan<<<1, 256, 0, stream>>>(cntK, cntU, cntI, kg_boff, ui_boff, iu_boff,
                                         kg_g, ui_g, iu_g);
    k_binB_all<<<NB_BKG + NB_B8 + NB_B8, 256, 0, stream>>>(eh, et, etype, kg_g, kg_tmp,
                                                           iu, ii, iwf,
                                                           ui_g, ui_tmp, iu_g, iu_tmp);
    k_binC_all<<<NB_CKG + NB_CUI + NB_CIU, 256, 0, stream>>>(kg_tmp, kg_boff, kg_tr, kg_off,
                                                             ui_tmp, ui_boff, ui_iw, ui_off,
                                                             iu_tmp, iu_boff, iu_iw, iu_off);

    // ---- layer 0 ----
    k_layer<true, false><<<NEB + NUB, 256, 0, stream>>>(qmH, relH, entHa, usrHa,
                                                        kg_off, kg_tr, iu_off, iu_iw,
                                                        ui_off, ui_iw,
                                                        eacc, entHb, uacc, usrHb,
                                                        nullptr, nullptr, nullptr);
    // ---- layer 1 (folds k_final) ----
    k_gemm_h<<<NE / 16, 256, 0, stream>>>(entHb, wqf, qmH);
    k_layer<false, true><<<NEB + NUB, 256, 0, stream>>>(qmH, relH, entHb, usrHb,
                                                        kg_off, kg_tr, iu_off, iu_iw,
                                                        ui_off, ui_iw,
                                                        eacc, nullptr, uacc, nullptr,
                                                        ent0, usr0, out);
}

// Round 11
// 452.562 us; speedup vs baseline: 1.1209x; 1.0323x over previous
//
#include <hip/hip_runtime.h>
#include <hip/hip_fp16.h>

#define NU 50000
#define NE 100000
#define DIM 64
#define NRELS 16
#define EKG 1500000
#define EIN 1000000

#define KG_CHUNK 8192
#define KG_NBUCK ((NE + 511) >> 9)   // 196
#define B8_CHUNK 4096
#define KG_CAP 9216
#define C8_CAP 6656

#define NEB (NE / 4)                 // 25000 ent blocks
#define NUB (NU / 4)                 // 12500 usr blocks

#define NB_BKG ((EKG + KG_CHUNK - 1) / KG_CHUNK)   // 184
#define NB_B8  ((EIN + B8_CHUNK - 1) / B8_CHUNK)   // 245
#define NB_CKG KG_NBUCK                             // 196
#define NB_CUI ((NU + 255) >> 8)                    // 196
#define NB_CIU ((NE + 511) >> 9)                    // 196

#define NB_PREP_H 512
#define NB_PREP_C 3125                              // (NU*16)/256
#define NB_PREP_G (NE / 16)                         // 6250

typedef _Float16 f16x2 __attribute__((ext_vector_type(2)));

union U16 { int4 v; __half2 h[4]; };
union H4 { int2 i2; __half2 h[2]; };

__device__ __forceinline__ float fdot2a(__half2 a, __half2 b, float c) {
#if __has_builtin(__builtin_amdgcn_fdot2)
    union { __half2 h; f16x2 v; } ua, ub;
    ua.h = a; ub.h = b;
    return __builtin_amdgcn_fdot2(ua.v, ub.v, c, false);
#else
    return c + __half2float(a.x) * __half2float(b.x) + __half2float(a.y) * __half2float(b.y);
#endif
}

// sum over each 4-lane quad via DPP (score reduce; head = quad)
__device__ __forceinline__ float dpp_red4(float p) {
    int t;
    t = __builtin_amdgcn_update_dpp(0, __float_as_int(p), 0xB1, 0xF, 0xF, true);  // quad_perm xor1
    p += __int_as_float(t);
    t = __builtin_amdgcn_update_dpp(0, __float_as_int(p), 0x4E, 0xF, 0xF, true);  // quad_perm xor2
    p += __int_as_float(t);
    return p;
}

// ---- merged prep: blocks [0,512) hist, [512,3637) usr/rel cast, [3637,9887) gemm_f+ent cast
struct SmP {
    union {
        struct { int sK[256], sU[256], sI[256]; } h;
        struct { float sW[64 * 64]; float sR[16 * 64]; } g;
    } u;
};

__global__ __launch_bounds__(256) void k_prep(const int* __restrict__ eh,
        const int* __restrict__ iu, const int* __restrict__ ii,
        int* __restrict__ cntK, int* __restrict__ cntU, int* __restrict__ cntI,
        const float4* __restrict__ u4, const float4* __restrict__ r4,
        int2* __restrict__ uH, int2* __restrict__ rH,
        const float* __restrict__ ent, const float* __restrict__ wq,
        __half* __restrict__ qmH, __half* __restrict__ entH) {
    __shared__ SmP sm;
    int bid = blockIdx.x;
    int t = threadIdx.x;
    if (bid < NB_PREP_H) {
        // ---- bucket-level histogram (LDS-privatized) ----
        sm.u.h.sK[t] = 0; sm.u.h.sU[t] = 0; sm.u.h.sI[t] = 0;
        __syncthreads();
        int stride = NB_PREP_H * 256;
        for (int e = bid * 256 + t; e < EKG; e += stride)
            atomicAdd(&sm.u.h.sK[eh[e] >> 9], 1);
        for (int e = bid * 256 + t; e < EIN; e += stride) {
            atomicAdd(&sm.u.h.sU[iu[e] >> 8], 1);
            atomicAdd(&sm.u.h.sI[ii[e] >> 9], 1);
        }
        __syncthreads();
        if (sm.u.h.sK[t]) atomicAdd(&cntK[t], sm.u.h.sK[t]);
        if (sm.u.h.sU[t]) atomicAdd(&cntU[t], sm.u.h.sU[t]);
        if (sm.u.h.sI[t]) atomicAdd(&cntI[t], sm.u.h.sI[t]);
    } else if (bid < NB_PREP_H + NB_PREP_C) {
        // ---- fp16 cast for usr + rel ----
        int i = (bid - NB_PREP_H) * 256 + t;
        if (i < NU * 16) {
            float4 v = u4[i];
            H4 o; o.h[0] = __floats2half2_rn(v.x, v.y); o.h[1] = __floats2half2_rn(v.z, v.w);
            uH[i] = o.i2;
        }
        if (i < NRELS * 16) {
            float4 v = r4[i];
            H4 o; o.h[0] = __floats2half2_rn(v.x, v.y); o.h[1] = __floats2half2_rn(v.z, v.w);
            rH[i] = o.i2;
        }
    } else {
        // ---- qm = ent0 @ WQ -> fp16, plus ent0 -> fp16 mirror ----
        for (int i = t; i < 4096; i += 256) sm.u.g.sW[i] = wq[i];
        long row0 = (long)(bid - NB_PREP_H - NB_PREP_C) * 16;
        for (int i = t; i < 1024; i += 256) sm.u.g.sR[i] = ent[row0 * 64 + i];
        __syncthreads();
        int r = t >> 4, cg = t & 15;
        const float4* sW4 = (const float4*)sm.u.g.sW;
        const float4* sR4 = (const float4*)sm.u.g.sR;
        float4 acc = {0.f, 0.f, 0.f, 0.f};
#pragma unroll
        for (int k = 0; k < 64; k++) {
            float a = sm.u.g.sR[r * 64 + k];
            float4 wv = sW4[k * 16 + cg];
            acc.x += a * wv.x; acc.y += a * wv.y; acc.z += a * wv.z; acc.w += a * wv.w;
        }
        H4 o;
        o.h[0] = __floats2half2_rn(acc.x, acc.y);
        o.h[1] = __floats2half2_rn(acc.z, acc.w);
        ((int2*)qmH)[(row0 + r) * 16 + cg] = o.i2;
        float4 ev = sR4[r * 16 + cg];
        H4 e;
        e.h[0] = __floats2half2_rn(ev.x, ev.y);
        e.h[1] = __floats2half2_rn(ev.z, ev.w);
        ((int2*)entH)[(row0 + r) * 16 + cg] = e.i2;
    }
}

// layer-1 gemm: fp16 ent input
__global__ __launch_bounds__(256) void k_gemm_h(const __half* __restrict__ ent,
                                                const float* __restrict__ wq,
                                                __half* __restrict__ qmH) {
    __shared__ float sW[64 * 64];
    __shared__ float sR[16 * 64];
    int t = threadIdx.x;
    for (int i = t; i < 4096; i += 256) sW[i] = wq[i];
    long row0 = (long)blockIdx.x * 16;
    const __half2* e2 = (const __half2*)ent;
    for (int i = t; i < 512; i += 256) {
        float2 f = __half22float2(e2[row0 * 32 + i]);
        sR[2 * i] = f.x; sR[2 * i + 1] = f.y;
    }
    __syncthreads();
    int r = t >> 4, cg = t & 15;
    const float4* sW4 = (const float4*)sW;
    float4 acc = {0.f, 0.f, 0.f, 0.f};
#pragma unroll
    for (int k = 0; k < 64; k++) {
        float a = sR[r * 64 + k];
        float4 wv = sW4[k * 16 + cg];
        acc.x += a * wv.x; acc.y += a * wv.y; acc.z += a * wv.z; acc.w += a * wv.w;
    }
    H4 o;
    o.h[0] = __floats2half2_rn(acc.x, acc.y);
    o.h[1] = __floats2half2_rn(acc.z, acc.w);
    ((int2*)qmH)[(row0 + r) * 16 + cg] = o.i2;
}

// ---- tiny scans: bucket counts -> bucket offsets + gcur init ----
__global__ __launch_bounds__(256) void k_bucket_scan(const int* __restrict__ cntK,
        const int* __restrict__ cntU, const int* __restrict__ cntI,
        int* __restrict__ kg_boff, int* __restrict__ ui_boff, int* __restrict__ iu_boff,
        int* __restrict__ kg_g, int* __restrict__ ui_g, int* __restrict__ iu_g) {
    __shared__ int sc[256];
    int t = threadIdx.x;
#define SCAN1(cnt, boff, gcur) { \
    int v = cnt[t]; sc[t] = v; __syncthreads(); \
    for (int o = 1; o < 256; o <<= 1) { \
        int u = (t >= o) ? sc[t - o] : 0; __syncthreads(); sc[t] += u; __syncthreads(); } \
    int e = sc[t] - v; boff[t] = e; gcur[t] = e; \
    __syncthreads(); }
    SCAN1(cntK, kg_boff, kg_g)
    SCAN1(cntU, ui_boff, ui_g)
    SCAN1(cntI, iu_boff, iu_g)
#undef SCAN1
}

// ---- merged pass B ----
struct SmB {
    union {
        struct { unsigned stage[KG_CHUNK]; int dest[KG_CHUNK]; } kg;
        struct { int2 stage[B8_CHUNK]; int dest[B8_CHUNK]; } b8;
    } u;
};

__device__ __forceinline__ void binB8_body(const int* __restrict__ key,
        const int* __restrict__ aux, const float* __restrict__ wv, int nE,
        int shift, int auxShift, int* __restrict__ gcur, int2* __restrict__ tmp,
        int cb, int2* stage, int* dest,
        int* cnt, int* boff, int* gbase, int* curl, int* sc) {
    int t = threadIdx.x;
    int base = cb * B8_CHUNK;
    int nloc = nE - base; if (nloc > B8_CHUNK) nloc = B8_CHUNK;
    cnt[t] = 0;
    __syncthreads();
    for (int i = t; i < nloc; i += 256)
        atomicAdd(&cnt[key[base + i] >> shift], 1);
    __syncthreads();
    int v = cnt[t];
    sc[t] = v;
    __syncthreads();
    for (int o = 1; o < 256; o <<= 1) {
        int u = (t >= o) ? sc[t - o] : 0;
        __syncthreads();
        sc[t] += u;
        __syncthreads();
    }
    boff[t] = sc[t] - v;
    curl[t] = sc[t] - v;
    gbase[t] = atomicAdd(&gcur[t], v);
    __syncthreads();
    int lowmask = (1 << shift) - 1;
    for (int i = t; i < nloc; i += 256) {
        int e = base + i;
        int k = key[e];
        int b = k >> shift;
        int2 pay;
        pay.x = aux[e] | ((k & lowmask) << auxShift);
        pay.y = __float_as_int(wv[e]);
        int pos = atomicAdd(&curl[b], 1);
        stage[pos] = pay;
        dest[pos] = gbase[b] + (pos - boff[b]);
    }
    __syncthreads();
    for (int s = t; s < nloc; s += 256) tmp[dest[s]] = stage[s];
}

__global__ __launch_bounds__(256) void k_binB_all(const int* __restrict__ eh,
        const int* __restrict__ et, const int* __restrict__ ety,
        int* __restrict__ kg_g, unsigned* __restrict__ kg_tmp,
        const int* __restrict__ iu, const int* __restrict__ ii,
        const float* __restrict__ iwf,
        int* __restrict__ ui_g, int2* __restrict__ ui_tmp,
        int* __restrict__ iu_g, int2* __restrict__ iu_tmp) {
    __shared__ SmB sm;
    __shared__ int cnt[256], boff[256], gbase[256], curl[256], sc[256];
    int bid = blockIdx.x;
    int t = threadIdx.x;
    if (bid < NB_BKG) {
        int base = bid * KG_CHUNK;
        int nloc = EKG - base; if (nloc > KG_CHUNK) nloc = KG_CHUNK;
        for (int i = t; i < KG_NBUCK; i += 256) cnt[i] = 0;
        __syncthreads();
        for (int i = t; i < nloc; i += 256)
            atomicAdd(&cnt[eh[base + i] >> 9], 1);
        __syncthreads();
        int v = (t < KG_NBUCK) ? cnt[t] : 0;
        sc[t] = v;
        __syncthreads();
        for (int o = 1; o < 256; o <<= 1) {
            int u = (t >= o) ? sc[t - o] : 0;
            __syncthreads();
            sc[t] += u;
            __syncthreads();
        }
        if (t < KG_NBUCK) {
            boff[t] = sc[t] - v;
            curl[t] = sc[t] - v;
            gbase[t] = atomicAdd(&kg_g[t], v);
        }
        __syncthreads();
        for (int i = t; i < nloc; i += 256) {
            int e = base + i;
            int h = eh[e];
            int b = h >> 9;
            unsigned pay = (unsigned)et[e] | ((unsigned)(ety[e] - 1) << 17)
                         | ((unsigned)(h & 511) << 21);
            int pos = atomicAdd(&curl[b], 1);
            sm.u.kg.stage[pos] = pay;
            sm.u.kg.dest[pos] = gbase[b] + (pos - boff[b]);
        }
        __syncthreads();
        for (int s = t; s < nloc; s += 256) kg_tmp[sm.u.kg.dest[s]] = sm.u.kg.stage[s];
    } else if (bid < NB_BKG + NB_B8) {
        binB8_body(iu, ii, iwf, EIN, 8, 17, ui_g, ui_tmp, bid - NB_BKG,
                   sm.u.b8.stage, sm.u.b8.dest, cnt, boff, gbase, curl, sc);
    } else {
        binB8_body(ii, iu, iwf, EIN, 9, 16, iu_g, iu_tmp, bid - NB_BKG - NB_B8,
                   sm.u.b8.stage, sm.u.b8.dest, cnt, boff, gbase, curl, sc);
    }
}

// ---- merged pass C ----
struct SmC {
    union {
        unsigned kgstage[KG_CAP];
        int2 c8stage[C8_CAP];
    } u;
};

__device__ __forceinline__ void binC8_body(const int2* __restrict__ tmp,
        const int* __restrict__ boffg, int2* __restrict__ dst, int* __restrict__ off,
        int nnodes, int shift, int auxShift, int lb, int nb,
        int2* stage, int* curl, int* sc) {
    int b = lb;
    int nbase = b << shift;
    int nlim = nnodes - nbase; if (nlim > (1 << shift)) nlim = 1 << shift;
    if (nlim <= 0) return;
    int t = threadIdx.x;
    int r0 = boffg[b];
    int r1 = boffg[b + 1];
    int cntb = r1 - r0;
    int lowmask = (1 << shift) - 1;
    curl[t] = 0; curl[t + 256] = 0;
    __syncthreads();
    for (int s = t; s < cntb; s += 256)
        atomicAdd(&curl[(tmp[r0 + s].x >> auxShift) & lowmask], 1);
    __syncthreads();
    int v0 = curl[2 * t], v1 = curl[2 * t + 1];
    int s2 = v0 + v1;
    sc[t] = s2;
    __syncthreads();
    for (int o = 1; o < 256; o <<= 1) {
        int u = (t >= o) ? sc[t - o] : 0;
        __syncthreads();
        sc[t] += u;
        __syncthreads();
    }
    int excl = sc[t] - s2;
    curl[2 * t] = excl;
    curl[2 * t + 1] = excl + v0;
    if (2 * t < nlim) off[nbase + 2 * t] = r0 + excl;
    if (2 * t + 1 < nlim) off[nbase + 2 * t + 1] = r0 + excl + v0;
    if (b == nb - 1 && t == 0) off[nbase + nlim] = r1;  // sentinel
    __syncthreads();
    if (cntb <= C8_CAP) {
        for (int s = t; s < cntb; s += 256) {
            int2 pay = tmp[r0 + s];
            int l = (pay.x >> auxShift) & lowmask;
            int pos = atomicAdd(&curl[l], 1);
            stage[pos] = pay;
        }
        __syncthreads();
        for (int s = t; s < cntb; s += 256) dst[r0 + s] = stage[s];
    } else {
        for (int s = t; s < cntb; s += 256) {
            int2 pay = tmp[r0 + s];
            int l = (pay.x >> auxShift) & lowmask;
            int pos = atomicAdd(&curl[l], 1);
            dst[r0 + pos] = pay;
        }
    }
}

__global__ __launch_bounds__(256) void k_binC_all(const unsigned* __restrict__ kg_tmp,
        const int* __restrict__ kg_boff, unsigned* __restrict__ kg_tr, int* __restrict__ kg_off,
        const int2* __restrict__ ui_tmp, const int* __restrict__ ui_boff,
        int2* __restrict__ ui_iw, int* __restrict__ ui_off,
        const int2* __restrict__ iu_tmp, const int* __restrict__ iu_boff,
        int2* __restrict__ iu_iw, int* __restrict__ iu_off) {
    __shared__ SmC sm;
    __shared__ int curl[512];
    __shared__ int sc[256];
    int bid = blockIdx.x;
    int t = threadIdx.x;
    if (bid < NB_CKG) {
        int b = bid;
        int nbase = b << 9;
        int nlim = NE - nbase; if (nlim > 512) nlim = 512;
        if (nlim <= 0) return;
        int r0 = kg_boff[b];
        int r1 = kg_boff[b + 1];
        int cntb = r1 - r0;
        curl[t] = 0; curl[t + 256] = 0;
        __syncthreads();
        for (int s = t; s < cntb; s += 256)
            atomicAdd(&curl[(kg_tmp[r0 + s] >> 21) & 511], 1);
        __syncthreads();
        int v0 = curl[2 * t], v1 = curl[2 * t + 1];
        int s2 = v0 + v1;
        sc[t] = s2;
        __syncthreads();
        for (int o = 1; o < 256; o <<= 1) {
            int u = (t >= o) ? sc[t - o] : 0;
            __syncthreads();
            sc[t] += u;
            __syncthreads();
        }
        int excl = sc[t] - s2;
        curl[2 * t] = excl;
        curl[2 * t + 1] = excl + v0;
        if (2 * t < nlim) kg_off[nbase + 2 * t] = r0 + excl;
        if (2 * t + 1 < nlim) kg_off[nbase + 2 * t + 1] = r0 + excl + v0;
        if (b == NB_CKG - 1 && t == 0) kg_off[nbase + nlim] = r1;   // sentinel off[NE]
        __syncthreads();
        if (cntb <= KG_CAP) {
            for (int s = t; s < cntb; s += 256) {
                unsigned pay = kg_tmp[r0 + s];
                int l = (pay >> 21) & 511;
                int pos = atomicAdd(&curl[l], 1);
                sm.u.kgstage[pos] = pay;
            }
            __syncthreads();
            for (int s = t; s < cntb; s += 256) kg_tr[r0 + s] = sm.u.kgstage[s];
        } else {
            for (int s = t; s < cntb; s += 256) {
                unsigned pay = kg_tmp[r0 + s];
                int l = (pay >> 21) & 511;
                int pos = atomicAdd(&curl[l], 1);
                kg_tr[r0 + pos] = pay;
            }
        }
    } else if (bid < NB_CKG + NB_CUI) {
        binC8_body(ui_tmp, ui_boff, ui_iw, ui_off, NU, 8, 17,
                   bid - NB_CKG, NB_CUI, sm.u.c8stage, curl, sc);
    } else {
        binC8_body(iu_tmp, iu_boff, iu_iw, iu_off, NE, 9, 16,
                   bid - NB_CKG - NB_CUI, NB_CIU, sm.u.c8stage, curl, sc);
    }
}

// ---- fused per-layer kernel. f16 packed accumulate (R10, verified). NEW: row
// gathers software-pipelined one full step ahead (payload two ahead) so each
// step's 24 random row-loads are in flight during the previous step's compute.
// Math/order bit-identical; final phantom prefetch uses clamped indices.
// FIRST=true: eacc/uacc stores; FINAL=true: folds k_final epilogue.
template<bool FIRST, bool FINAL>
__global__ __launch_bounds__(256) void k_layer(const __half* __restrict__ qmH,
        const __half* __restrict__ relH, const __half* __restrict__ entH,
        const __half* __restrict__ usrH,
        const int* __restrict__ kg_off, const unsigned* __restrict__ kg_tr,
        const int* __restrict__ iu_off, const int2* __restrict__ iu_iw,
        const int* __restrict__ ui_off, const int2* __restrict__ ui_iw,
        float* __restrict__ eacc, __half* __restrict__ entHout,
        float* __restrict__ uacc, __half* __restrict__ usrHout,
        const float* __restrict__ ent0, const float* __restrict__ usr0,
        float* __restrict__ out) {
    int w = __builtin_amdgcn_readfirstlane(threadIdx.x >> 6);
    int lane = threadIdx.x & 63;
    int sub = lane >> 3;          // edge slot 0..7
    int li  = lane & 7;           // dims 8li..8li+7
    const float SC = 0.17677669529663687f; // 1/sqrt(32)
    const float NEG = -1e30f;
    const float inv3 = 1.f / 3.f;
    const int4* qmI  = (const int4*)qmH;
    const int4* entI = (const int4*)entH;
    const int4* relI = (const int4*)relH;
    const int4* usrI = (const int4*)usrH;
    const __half2 hz = __floats2half2_rn(0.f, 0.f);

    if (blockIdx.x < NEB) {
        // ================= entity path =================
        int node = blockIdx.x * 4 + w;
        U16 qh; qh.v = qmI[(long)node * 8 + li];
        int b0 = kg_off[node], b1 = kg_off[node + 1];
        int deg = b1 - b0;

        float ssum = 0.f;
        float acc[8] = {0.f, 0.f, 0.f, 0.f, 0.f, 0.f, 0.f, 0.f};
        if (deg > 0) {
            __half2 acc_h[4] = {hz, hz, hz, hz};
            int i0 = b0 + sub;
            unsigned tr_c = kg_tr[i0 < b1 ? i0 : b1 - 1];
            int tl0 = tr_c & 0x1FFFF, rr0 = (tr_c >> 17) & 15;
            U16 rl_c, qt_c, ev_c;
            rl_c.v = relI[rr0 * 8 + li];
            qt_c.v = qmI[(long)tl0 * 8 + li];
            ev_c.v = entI[(long)tl0 * 8 + li];
            int i1 = i0 + 8;
            unsigned tr_n = kg_tr[i1 < b1 ? i1 : b1 - 1];
            for (int s = b0; s < b1; s += 8) {
                int i2 = s + 16 + sub;
                unsigned tr_2 = kg_tr[i2 < b1 ? i2 : b1 - 1];     // payload 2 ahead
                int tln = tr_n & 0x1FFFF, rrn = (tr_n >> 17) & 15;
                U16 rl_n, qt_n, ev_n;                             // rows 1 ahead
                rl_n.v = relI[rrn * 8 + li];
                qt_n.v = qmI[(long)tln * 8 + li];
                ev_n.v = entI[(long)tln * 8 + li];
                bool has = (s + sub) < b1;
                float p = 0.f;
#pragma unroll
                for (int k = 0; k < 4; k++) {
                    __half2 kk = __hmul2(qt_c.h[k], rl_c.h[k]);
                    p = fdot2a(qh.h[k], kk, p);
                }
                p = dpp_red4(p);
                float e = __expf(has ? p * SC : NEG);
                ssum += e;
                __half2 e2 = __float2half2_rn(e);
#pragma unroll
                for (int k = 0; k < 4; k++)
                    acc_h[k] = __hfma2(__hmul2(ev_c.h[k], rl_c.h[k]), e2, acc_h[k]);
                tr_c = tr_n; tr_n = tr_2;
                rl_c = rl_n; qt_c = qt_n; ev_c = ev_n;
            }
#pragma unroll
            for (int k = 0; k < 4; k++) {
                float2 vf = __half22float2(acc_h[k]);
                acc[2 * k] = vf.x; acc[2 * k + 1] = vf.y;
            }
#pragma unroll
            for (int o = 8; o <= 32; o <<= 1) {
                ssum += __shfl_xor(ssum, o, 64);
#pragma unroll
                for (int k = 0; k < 8; k++) acc[k] += __shfl_xor(acc[k], o, 64);
            }
            float inv = 1.f / ssum;
#pragma unroll
            for (int k = 0; k < 8; k++) acc[k] *= inv;
            float ss = 0.f;
#pragma unroll
            for (int k = 0; k < 8; k++) ss += acc[k] * acc[k];
            ss += __shfl_xor(ss, 1, 64);
            ss += __shfl_xor(ss, 2, 64);
            ss += __shfl_xor(ss, 4, 64);
            float nsc = 1.f / fmaxf(sqrtf(ss), 1e-12f);
#pragma unroll
            for (int k = 0; k < 8; k++) acc[k] *= nsc;
        }

        // user -> entity gather (f16 packed accumulate, pipelined)
        int c0 = iu_off[node], c1 = iu_off[node + 1];
        if (c1 > c0) {
            __half2 ua_h[4] = {hz, hz, hz, hz};
            int j0 = c0 + sub;
            int2 pw_c = iu_iw[j0 < c1 ? j0 : c1 - 1];
            U16 uu_c; uu_c.v = usrI[(long)(pw_c.x & 0xFFFF) * 8 + li];
            int j1 = j0 + 8;
            int2 pw_n = iu_iw[j1 < c1 ? j1 : c1 - 1];
            for (int t2 = c0; t2 < c1; t2 += 8) {
                int j2 = t2 + 16 + sub;
                int2 pw_2 = iu_iw[j2 < c1 ? j2 : c1 - 1];
                U16 uu_n; uu_n.v = usrI[(long)(pw_n.x & 0xFFFF) * 8 + li];
                bool has = (t2 + sub) < c1;
                float wv = has ? __int_as_float(pw_c.y) : 0.f;
                __half2 wv2 = __float2half2_rn(wv);
#pragma unroll
                for (int k = 0; k < 4; k++)
                    ua_h[k] = __hfma2(uu_c.h[k], wv2, ua_h[k]);
                pw_c = pw_n; pw_n = pw_2; uu_c = uu_n;
            }
            float ua[8];
#pragma unroll
            for (int k = 0; k < 4; k++) {
                float2 uf = __half22float2(ua_h[k]);
                ua[2 * k] = uf.x; ua[2 * k + 1] = uf.y;
            }
#pragma unroll
            for (int o = 8; o <= 32; o <<= 1) {
#pragma unroll
                for (int k = 0; k < 8; k++) ua[k] += __shfl_xor(ua[k], o, 64);
            }
#pragma unroll
            for (int k = 0; k < 8; k++) acc[k] += ua[k];
        }

        if (sub == 0) {
            long base = (long)node * 16 + 2 * li;
            float4* eacc4 = (float4*)eacc;
            float4 e0, e1;
            if (FIRST) {
                e0.x = acc[0]; e0.y = acc[1]; e0.z = acc[2]; e0.w = acc[3];
                e1.x = acc[4]; e1.y = acc[5]; e1.z = acc[6]; e1.w = acc[7];
            } else {
                e0 = eacc4[base]; e1 = eacc4[base + 1];
                e0.x += acc[0]; e0.y += acc[1]; e0.z += acc[2]; e0.w += acc[3];
                e1.x += acc[4]; e1.y += acc[5]; e1.z += acc[6]; e1.w += acc[7];
            }
            if (!FINAL) {
                eacc4[base] = e0; eacc4[base + 1] = e1;
                U16 ho;
                ho.h[0] = __floats2half2_rn(acc[0], acc[1]);
                ho.h[1] = __floats2half2_rn(acc[2], acc[3]);
                ho.h[2] = __floats2half2_rn(acc[4], acc[5]);
                ho.h[3] = __floats2half2_rn(acc[6], acc[7]);
                ((int4*)entHout)[(long)node * 8 + li] = ho.v;
            } else {
                const float4* a4 = (const float4*)ent0;
                float4 a0 = a4[base], a1 = a4[base + 1];
                float4 o0, o1;
                o0.x = (a0.x + e0.x) * inv3; o0.y = (a0.y + e0.y) * inv3;
                o0.z = (a0.z + e0.z) * inv3; o0.w = (a0.w + e0.w) * inv3;
                o1.x = (a1.x + e1.x) * inv3; o1.y = (a1.y + e1.y) * inv3;
                o1.z = (a1.z + e1.z) * inv3; o1.w = (a1.w + e1.w) * inv3;
                float4* oute = (float4*)out + (long)NU * 16;
                oute[base] = o0; oute[base + 1] = o1;
            }
        }
    } else {
        // ================= user path (f16 packed accumulate, pipelined) =================
        int node = (blockIdx.x - NEB) * 4 + w;
        int b0 = ui_off[node], b1 = ui_off[node + 1];
        float ax[8] = {0.f, 0.f, 0.f, 0.f, 0.f, 0.f, 0.f, 0.f};
        if (b1 > b0) {
            __half2 ax_h[4] = {hz, hz, hz, hz};
            int j0 = b0 + sub;
            int2 pw_c = ui_iw[j0 < b1 ? j0 : b1 - 1];
            U16 uu_c; uu_c.v = entI[(long)(pw_c.x & 0x1FFFF) * 8 + li];
            int j1 = j0 + 8;
            int2 pw_n = ui_iw[j1 < b1 ? j1 : b1 - 1];
            for (int s = b0; s < b1; s += 8) {
                int j2 = s + 16 + sub;
                int2 pw_2 = ui_iw[j2 < b1 ? j2 : b1 - 1];
                U16 uu_n; uu_n.v = entI[(long)(pw_n.x & 0x1FFFF) * 8 + li];
                bool has = (s + sub) < b1;
                float wv = has ? __int_as_float(pw_c.y) : 0.f;
                __half2 wv2 = __float2half2_rn(wv);
#pragma unroll
                for (int k = 0; k < 4; k++)
                    ax_h[k] = __hfma2(uu_c.h[k], wv2, ax_h[k]);
                pw_c = pw_n; pw_n = pw_2; uu_c = uu_n;
            }
#pragma unroll
            for (int k = 0; k < 4; k++) {
                float2 uf = __half22float2(ax_h[k]);
                ax[2 * k] = uf.x; ax[2 * k + 1] = uf.y;
            }
#pragma unroll
            for (int o = 8; o <= 32; o <<= 1) {
#pragma unroll
                for (int k = 0; k < 8; k++) ax[k] += __shfl_xor(ax[k], o, 64);
            }
        }
        if (sub == 0) {
            long base = (long)node * 16 + 2 * li;
            float4* uacc4 = (float4*)uacc;
            float4 u0, u1;
            if (FIRST) {
                u0.x = ax[0]; u0.y = ax[1]; u0.z = ax[2]; u0.w = ax[3];
                u1.x = ax[4]; u1.y = ax[5]; u1.z = ax[6]; u1.w = ax[7];
            } else {
                u0 = uacc4[base]; u1 = uacc4[base + 1];
                u0.x += ax[0]; u0.y += ax[1]; u0.z += ax[2]; u0.w += ax[3];
                u1.x += ax[4]; u1.y += ax[5]; u1.z += ax[6]; u1.w += ax[7];
            }
            if (!FINAL) {
                uacc4[base] = u0; uacc4[base + 1] = u1;
                U16 ho;
                ho.h[0] = __floats2half2_rn(ax[0], ax[1]);
                ho.h[1] = __floats2half2_rn(ax[2], ax[3]);
                ho.h[2] = __floats2half2_rn(ax[4], ax[5]);
                ho.h[3] = __floats2half2_rn(ax[6], ax[7]);
                ((int4*)usrHout)[(long)node * 8 + li] = ho.v;
            } else {
                const float4* a4 = (const float4*)usr0;
                float4 a0 = a4[base], a1 = a4[base + 1];
                float4 o0, o1;
                o0.x = (a0.x + u0.x) * inv3; o0.y = (a0.y + u0.y) * inv3;
                o0.z = (a0.z + u0.z) * inv3; o0.w = (a0.w + u0.w) * inv3;
                o1.x = (a1.x + u1.x) * inv3; o1.y = (a1.y + u1.y) * inv3;
                o1.z = (a1.z + u1.z) * inv3; o1.w = (a1.w + u1.w) * inv3;
                float4* outu = (float4*)out;
                outu[base] = o0; outu[base + 1] = o1;
            }
        }
    }
}

extern "C" void kernel_launch(void* const* d_in, const int* in_sizes, int n_in,
                              void* d_out, int out_size, void* d_ws, size_t ws_size,
                              hipStream_t stream) {
    const float* usr0  = (const float*)d_in[1];
    const float* ent0  = (const float*)d_in[2];
    const int*   inter = (const int*)d_in[3];
    const float* iwf   = (const float*)d_in[4];
    const int*   eidx  = (const int*)d_in[5];
    const int*   etype = (const int*)d_in[6];
    const float* relf  = (const float*)d_in[7];
    const float* wqf   = (const float*)d_in[8];
    float* out = (float*)d_out;

    const int* eh = eidx;
    const int* et = eidx + EKG;
    const int* iu = inter;
    const int* ii = inter + EIN;

    // ---- workspace layout (4B words) ----
    float* p = (float*)d_ws;
    float* eacc = p;  p += (long)NE * DIM;
    float* uacc = p;  p += (long)NU * DIM;
    __half* qmH   = (__half*)p;  p += (long)NE * DIM / 2;
    __half* entHa = (__half*)p;  p += (long)NE * DIM / 2;
    __half* entHb = (__half*)p;  p += (long)NE * DIM / 2;
    __half* usrHa = (__half*)p;  p += (long)NU * DIM / 2;
    __half* usrHb = (__half*)p;  p += (long)NU * DIM / 2;
    __half* relH  = (__half*)p;  p += (long)NRELS * DIM / 2;
    int* cntK = (int*)p;        p += 256;
    int* cntU = (int*)p;        p += 256;
    int* cntI = (int*)p;        p += 256;
    int* kg_boff = (int*)p;     p += 256;
    int* ui_boff = (int*)p;     p += 256;
    int* iu_boff = (int*)p;     p += 256;
    int* kg_off = (int*)p;      p += NE + 2;
    int* ui_off = (int*)p;      p += NU + 2;
    int* iu_off = (int*)p;      p += NE + 2;
    int* kg_g   = (int*)p;      p += 256;
    int* ui_g   = (int*)p;      p += 256;
    int* iu_g   = (int*)p;      p += 256;
    unsigned* kg_tr  = (unsigned*)p; p += EKG;
    unsigned* kg_tmp = (unsigned*)p; p += EKG;
    int2* ui_iw  = (int2*)p;    p += (long)EIN * 2;
    int2* ui_tmp = (int2*)p;    p += (long)EIN * 2;
    int2* iu_iw  = (int2*)p;    p += (long)EIN * 2;
    int2* iu_tmp = (int2*)p;    p += (long)EIN * 2;

    // ---- init: bucket counters only ----
    hipMemsetAsync(cntK, 0, (size_t)768 * 4, stream);

    // ---- prep: hist + usr/rel cast + gemm_f (independent; one dispatch) ----
    k_prep<<<NB_PREP_H + NB_PREP_C + NB_PREP_G, 256, 0, stream>>>(
        eh, iu, ii, cntK, cntU, cntI,
        (const float4*)usr0, (const float4*)relf, (int2*)usrHa, (int2*)relH,
        ent0, wqf, qmH, entHa);

    // ---- CSR build ----
    k_bucket_scan<<<1, 256, 0, stream>>>(cntK, cntU, cntI, kg_boff, ui_boff, iu_boff,
                                         kg_g, ui_g, iu_g);
    k_binB_all<<<NB_BKG + NB_B8 + NB_B8, 256, 0, stream>>>(eh, et, etype, kg_g, kg_tmp,
                                                           iu, ii, iwf,
                                                           ui_g, ui_tmp, iu_g, iu_tmp);
    k_binC_all<<<NB_CKG + NB_CUI + NB_CIU, 256, 0, stream>>>(kg_tmp, kg_boff, kg_tr, kg_off,
                                                             ui_tmp, ui_boff, ui_iw, ui_off,
                                                             iu_tmp, iu_boff, iu_iw, iu_off);

    // ---- layer 0 ----
    k_layer<true, false><<<NEB + NUB, 256, 0, stream>>>(qmH, relH, entHa, usrHa,
                                                        kg_off, kg_tr, iu_off, iu_iw,
                                                        ui_off, ui_iw,
                                                        eacc, entHb, uacc, usrHb,
                                                        nullptr, nullptr, nullptr);
    // ---- layer 1 (folds k_final) ----
    k_gemm_h<<<NE / 16, 256, 0, stream>>>(entHb, wqf, qmH);
    k_layer<false, true><<<NEB + NUB, 256, 0, stream>>>(qmH, relH, entHb, usrHb,
                                                        kg_off, kg_tr, iu_off, iu_iw,
                                                        ui_off, ui_iw,
                                                        eacc, nullptr, uacc, nullptr,
                                                        ent0, usr0, out);
}